// Round 13
// baseline (199.628 us; speedup 1.0000x reference)
//
#include <hip/hip_runtime.h>
#include <hip/hip_bf16.h>
#include <math.h>

#define NEVENT 1024
#define NSTEP 64
#define NWINDOW 2048
#define NHID 128
#define NG 512
#define WPB 8   // windows per block in cls_k

typedef __attribute__((ext_vector_type(8))) short bf16x8;
typedef __attribute__((ext_vector_type(4))) float f32x4;

__device__ __forceinline__ unsigned short f2bf(float f){
  unsigned int u = __float_as_uint(f);
  return (unsigned short)((u + 0x7FFFu + ((u >> 16) & 1u)) >> 16);
}
__device__ __forceinline__ float sigm(float x){
  return __builtin_amdgcn_rcpf(1.0f + __expf(-x));
}
__device__ __forceinline__ float tanh_f(float x){
  float e = __expf(2.0f * x);
  return 1.0f - 2.0f * __builtin_amdgcn_rcpf(e + 1.0f);
}
// lgkm-only barrier: LDS ordering without draining vmcnt (global gathers stay in flight)
__device__ __forceinline__ void lgkm_barrier(){
  asm volatile("s_waitcnt lgkmcnt(0)" ::: "memory");
  __builtin_amdgcn_s_barrier();
}
// packed f32x2 -> bf16x2, RNE (bit-identical to f2bf); dst[15:0]=bf16(a), dst[31:16]=bf16(b)
__device__ __forceinline__ unsigned int cvtpk_bf16(float a, float b){
  unsigned int r;
  asm("v_cvt_pk_bf16_f32 %0, %1, %2" : "=v"(r) : "v"(a), "v"(b));
  return r;
}
// swizzle byte offset within h tile: spread rows across 16B slots
#define SWZ(row, byte) ((byte) ^ (((row) & 7) << 4))

// merged prep kernel:
//  blocks [0,512):   LDS-tiled transpose qWih0 [512][1024] -> qWqT [1024][512]
//  blocks [512,768): LDS-tiled transpose clsW  [1024][256] -> clsWT [256][1024]
//  blocks [768,960): pack6 (six W [512][128] f32 -> bf16 MFMA B-fragments)
__global__ __launch_bounds__(256)
void prep_k(const float* __restrict__ qWih0, float* __restrict__ qWqT,
            const float* __restrict__ clsW,  float* __restrict__ clsWT,
            const float* __restrict__ s0, const float* __restrict__ s1,
            const float* __restrict__ s2, const float* __restrict__ s3,
            const float* __restrict__ s4, const float* __restrict__ s5,
            unsigned short* __restrict__ dst)
{
  const int b = blockIdx.x;
  if (b < 768){
    // ---- tiled transpose: out[c][r] = in[r][c], both sides coalesced ----
    const float* in; float* out; int R, C, bb;
    if (b < 512){ in = qWih0; out = qWqT; R = NG;     C = NEVENT; bb = b; }
    else        { in = clsW;  out = clsWT; R = NEVENT; C = 2*NHID; bb = b - 512; }
    __shared__ float tl[32][33];
    const int nbx = C >> 5;
    const int by = bb / nbx, bx = bb - by*nbx;
    const int tx = threadIdx.x & 31, ty = threadIdx.x >> 5;
    #pragma unroll
    for (int k = 0; k < 4; ++k){
      int r = by*32 + ty + k*8;
      tl[ty + k*8][tx] = in[r*C + bx*32 + tx];
    }
    __syncthreads();
    #pragma unroll
    for (int k = 0; k < 4; ++k){
      int r = bx*32 + ty + k*8;               // out row = original col
      out[r*R + by*32 + tx] = tl[tx][ty + k*8];
    }
  } else {
    // ---- pack6: frag (kt,n): lane holds B[k][col], col=16n+(lane&15),
    // k=32kt+8*(lane>>4)+j, j=0..7 ----
    const int bb = b - 768;
    const int g = bb >> 5;
    const int i = (bb & 31)*256 + threadIdx.x;   // [0, 8192)
    const float* src = (g==0)?s0:(g==1)?s1:(g==2)?s2:(g==3)?s3:(g==4)?s4:s5;
    unsigned short* d = dst + g*65536;
    const int lane = i & 63; const int n = (i >> 6) & 31; const int kt = i >> 11;
    const int col = 16*n + (lane & 15);
    const int k0  = 32*kt + 8*(lane >> 4);
    #pragma unroll
    for (int j = 0; j < 8; ++j)
      d[i*8 + j] = f2bf(src[col*128 + k0 + j]);
  }
}

// R22 lstm = R21 lstm (verified 166.8us) with acc-init movs folded into MFMA
// C-in: L1 holds b1v[4] (f32x4) persistent and feeds it as kt0's C operand;
// quant-L0 keeps zr as f32x4[4] and feeds it as kt0's C operand (identical
// arithmetic -- the copy acc=zr is eliminated, peak liveness drops by 16 regs
// for one interval). Saves 32 v_mov issues/step/SIMD in an issue-saturated
// kernel (VALU 58% + MFMA 26%).
// Tripwires: absmax == 1.9531e-3 exactly; WRITE <= 11.5MB (else revert quant C-in).
__global__ __launch_bounds__(1024) __attribute__((amdgpu_waves_per_eu(4, 4)))
void lstm_fused_k(const int* __restrict__ seqtok,
    const float* __restrict__ sWih0,
    const float* __restrict__ sb0i, const float* __restrict__ sb0h,
    const float* __restrict__ sb1i, const float* __restrict__ sb1h,
    const float* __restrict__ qb0i, const float* __restrict__ qb0h,
    const float* __restrict__ qb1i, const float* __restrict__ qb1h,
    const unsigned short* __restrict__ pWhh0_s, const unsigned short* __restrict__ pWih1_s,
    const unsigned short* __restrict__ pWhh1_s,
    const unsigned short* __restrict__ pWhh0_q, const unsigned short* __restrict__ pWih1_q,
    const unsigned short* __restrict__ pWhh1_q,
    const float* __restrict__ qWqT,    // [1024][512]
    float* __restrict__ hseq, float* __restrict__ hq)
{
  __shared__ uint4 wih1[8192];                                            // 128 KB
  __shared__ __attribute__((aligned(16))) unsigned short h0buf[2][2048];  // 2 x 4KB
  __shared__ __attribute__((aligned(16))) unsigned short h1buf[2][2048];
  __shared__ int sAll[16*64];                                             // 4KB

  const int tid  = threadIdx.x;
  const int lane = tid & 63;
  const int w    = tid >> 6;            // wave id 0..15
  const bool quant = (blockIdx.x >= 128);
  const int blk  = quant ? (int)blockIdx.x - 128 : (int)blockIdx.x;
  const int w0   = blk * 16;

  // ---- prologue staging (all 16 waves) ----
  const uint4* wsrc = (const uint4*)(quant ? pWih1_q : pWih1_s);
  for (int i = tid; i < 8192; i += 1024) wih1[i] = wsrc[i];
  sAll[tid] = seqtok[w0*64 + tid];                       // [16 win][64 t] contiguous
  for (int i = tid; i < 2048; i += 1024){ h0buf[0][i] = 0; h1buf[0][i] = 0; }

  const int rbase = 4*(lane >> 4);         // window row base (D-layout)
  char* const h0base = (char*)h0buf;
  char* const h1base = (char*)h1buf;

  __syncthreads();   // barrier #0: staged data ready

  if (w < 8){
    // ================= L1 role: layer-1, phase C(t) =================
    const int nw   = w;
    const int jcol = 16*nw + (lane & 15);
    const float* b1i = quant ? qb1i : sb1i; const float* b1h = quant ? qb1h : sb1h;
    f32x4 b1v[4];                        // persistent broadcast bias (kt0 C-in)
    #pragma unroll
    for (int q = 0; q < 4; ++q){
      int col = 128*q + jcol; float b = b1i[col] + b1h[col];
      f32x4 v; v[0]=b; v[1]=b; v[2]=b; v[3]=b; b1v[q] = v;
    }
    const unsigned short* p1 = quant ? pWhh1_q : pWhh1_s;
    bf16x8 whh1f[4][4];
    #pragma unroll
    for (int q = 0; q < 4; ++q)
      #pragma unroll
      for (int kt = 0; kt < 4; ++kt)
        whh1f[q][kt] = *(const bf16x8*)(p1 + ((kt*32 + 8*q + nw)*64 + lane)*8);
    float c1[4] = {0,0,0,0};
    float* const houtp = quant ? hq : hseq;

    lgkm_barrier();    // barrier #1: pairs with L0's post-A(0) barrier -> h0[0] ready

    for (int t = 0; t < NSTEP-1; ++t){
      char* h0rd = h0base + ((t+1)&1)*4096;   // h0[t]
      char* h1rd = h1base + ((t  )&1)*4096;   // h1[t-1]
      char* h1wr = h1base + ((t+1)&1)*4096;   // h1[t]
      const int row = lane & 15;
      f32x4 acc[4];
      {  // kt = 0: C-in = b1v (no acc-init movs)
        int off = SWZ(row, row*256 + 0*64 + (lane>>4)*16);
        const bf16x8 a0 = *(const bf16x8*)(h0rd + off);
        const bf16x8 a1 = *(const bf16x8*)(h1rd + off);
        #pragma unroll
        for (int q = 0; q < 4; ++q){
          const bf16x8 wi = *(const bf16x8*)((const char*)wih1 + ((0*32 + 8*q + nw)*64 + lane)*16);
          acc[q] = __builtin_amdgcn_mfma_f32_16x16x32_bf16(a0, wi,          b1v[q], 0, 0, 0);
          acc[q] = __builtin_amdgcn_mfma_f32_16x16x32_bf16(a1, whh1f[q][0], acc[q], 0, 0, 0);
        }
      }
      #pragma unroll
      for (int kt = 1; kt < 4; ++kt){
        int off = SWZ(row, row*256 + kt*64 + (lane>>4)*16);
        const bf16x8 a0 = *(const bf16x8*)(h0rd + off);
        const bf16x8 a1 = *(const bf16x8*)(h1rd + off);
        #pragma unroll
        for (int q = 0; q < 4; ++q){
          const bf16x8 wi = *(const bf16x8*)((const char*)wih1 + ((kt*32 + 8*q + nw)*64 + lane)*16);
          acc[q] = __builtin_amdgcn_mfma_f32_16x16x32_bf16(a0, wi,           acc[q], 0, 0, 0);
          acc[q] = __builtin_amdgcn_mfma_f32_16x16x32_bf16(a1, whh1f[q][kt], acc[q], 0, 0, 0);
        }
      }
      {
        float hv[4];
        #pragma unroll
        for (int r = 0; r < 4; ++r){
          float iv = sigm(acc[0][r]), fv = sigm(acc[1][r]);
          float gv = tanh_f(acc[2][r]), ov = sigm(acc[3][r]);
          c1[r] = fv*c1[r] + iv*gv;
          hv[r] = ov * tanh_f(c1[r]);
        }
        unsigned int pk01 = cvtpk_bf16(hv[0], hv[1]);
        unsigned int pk23 = cvtpk_bf16(hv[2], hv[3]);
        *(unsigned short*)(h1wr + SWZ(rbase,   (rbase  )*256 + jcol*2)) = (unsigned short)pk01;
        *(unsigned short*)(h1wr + SWZ(rbase+1, (rbase+1)*256 + jcol*2)) = (unsigned short)(pk01 >> 16);
        *(unsigned short*)(h1wr + SWZ(rbase+2, (rbase+2)*256 + jcol*2)) = (unsigned short)pk23;
        *(unsigned short*)(h1wr + SWZ(rbase+3, (rbase+3)*256 + jcol*2)) = (unsigned short)(pk23 >> 16);
      }
      lgkm_barrier();
    }

    // ---- epilogue C(63): write global output only (L0 waves already done) ----
    {
      char* h0rd = h0base + 0*4096;           // h0[63] -> buf (63+1)&1 = 0
      char* h1rd = h1base + 1*4096;           // h1[62] -> buf 63&1 = 1
      const int row = lane & 15;
      f32x4 acc[4];
      {
        int off = SWZ(row, row*256 + 0*64 + (lane>>4)*16);
        const bf16x8 a0 = *(const bf16x8*)(h0rd + off);
        const bf16x8 a1 = *(const bf16x8*)(h1rd + off);
        #pragma unroll
        for (int q = 0; q < 4; ++q){
          const bf16x8 wi = *(const bf16x8*)((const char*)wih1 + ((0*32 + 8*q + nw)*64 + lane)*16);
          acc[q] = __builtin_amdgcn_mfma_f32_16x16x32_bf16(a0, wi,          b1v[q], 0, 0, 0);
          acc[q] = __builtin_amdgcn_mfma_f32_16x16x32_bf16(a1, whh1f[q][0], acc[q], 0, 0, 0);
        }
      }
      #pragma unroll
      for (int kt = 1; kt < 4; ++kt){
        int off = SWZ(row, row*256 + kt*64 + (lane>>4)*16);
        const bf16x8 a0 = *(const bf16x8*)(h0rd + off);
        const bf16x8 a1 = *(const bf16x8*)(h1rd + off);
        #pragma unroll
        for (int q = 0; q < 4; ++q){
          const bf16x8 wi = *(const bf16x8*)((const char*)wih1 + ((kt*32 + 8*q + nw)*64 + lane)*16);
          acc[q] = __builtin_amdgcn_mfma_f32_16x16x32_bf16(a0, wi,           acc[q], 0, 0, 0);
          acc[q] = __builtin_amdgcn_mfma_f32_16x16x32_bf16(a1, whh1f[q][kt], acc[q], 0, 0, 0);
        }
      }
      #pragma unroll
      for (int r = 0; r < 4; ++r){
        float iv = sigm(acc[0][r]), fv = sigm(acc[1][r]);
        float gv = tanh_f(acc[2][r]), ov = sigm(acc[3][r]);
        c1[r] = fv*c1[r] + iv*gv;
        float h = ov * tanh_f(c1[r]);
        int rw = rbase + r;
        houtp[(w0 + rw)*128 + jcol] = h;
      }
    }
  } else {
    // ================= L0 role: layer-0, phase A(t+1) =================
    const int nw   = w - 8;
    const int jcol = 16*nw + (lane & 15);
    const float* b0i = quant ? qb0i : sb0i; const float* b0h = quant ? qb0h : sb0h;
    float b0c[4];
    #pragma unroll
    for (int q = 0; q < 4; ++q){
      int col = 128*q + jcol;
      b0c[q] = b0i[col] + b0h[col];
    }
    const unsigned short* p0 = quant ? pWhh0_q : pWhh0_s;
    bf16x8 whh0f[4][4];
    #pragma unroll
    for (int q = 0; q < 4; ++q)
      #pragma unroll
      for (int kt = 0; kt < 4; ++kt)
        whh0f[q][kt] = *(const bf16x8*)(p0 + ((kt*32 + 8*q + nw)*64 + lane)*8);

    float c0[4] = {0,0,0,0};

    if (quant){
      // ---- quant arm: zr as f32x4[4]; kt0 MFMA C-in = zr (no acc copy) ----
      f32x4 zr[4];
      #pragma unroll
      for (int q = 0; q < 4; ++q){ f32x4 v; v[0]=b0c[q]; v[1]=b0c[q]; v[2]=b0c[q]; v[3]=b0c[q]; zr[q]=v; }
      // A(0): h[-1]=0; gather g(s_0) in place
      {
        float gvv[4][4];                // [q][r] transient
        #pragma unroll
        for (int r = 0; r < 4; ++r){
          int s = sAll[(rbase + r)*64 + 0];
          const float* gp = qWqT + s*512 + jcol;
          #pragma unroll
          for (int q = 0; q < 4; ++q) gvv[q][r] = gp[128*q];
        }
        float g0[4][4];
        #pragma unroll
        for (int q = 0; q < 4; ++q)
          #pragma unroll
          for (int r = 0; r < 4; ++r){ zr[q][r] += gvv[q][r]; g0[q][r] = zr[q][r]; }
        #pragma unroll
        for (int r = 0; r < 4; ++r){
          float iv = sigm(g0[0][r]);
          float gv = tanh_f(g0[2][r]);
          float ov = sigm(g0[3][r]);
          c0[r] = iv * gv;                 // f*c_prev = 0
          float h = ov * tanh_f(c0[r]);
          int row = rbase + r;
          *(unsigned short*)(h0base + 4096 + SWZ(row, row*256 + jcol*2)) = f2bf(h);  // h0[0] -> buf 1
        }
      }
      lgkm_barrier();    // barrier #1: h0[0] visible

      for (int t = 0; t < NSTEP-1; ++t){
        char* h0rd = h0base + ((t+1)&1)*4096;   // h0[t]
        char* h0wr = h0base + ((t  )&1)*4096;   // h0[t+1]
        const int row = lane & 15;
        // JIT gather g(s_{t+1}) -- issued first, consumed at zr update below;
        // latency hides in L0's matrix-pipe slack vs the L1 waves.
        float gvv[4][4];                // [q][r] transient
        #pragma unroll
        for (int r = 0; r < 4; ++r){
          int s = sAll[(rbase + r)*64 + t + 1];
          const float* gp = qWqT + s*512 + jcol;
          #pragma unroll
          for (int q = 0; q < 4; ++q) gvv[q][r] = gp[128*q];
        }
        #pragma unroll
        for (int q = 0; q < 4; ++q)
          #pragma unroll
          for (int r = 0; r < 4; ++r) zr[q][r] += gvv[q][r];
        f32x4 acc[4];
        {  // kt = 0: C-in = zr (no copy)
          int off = SWZ(row, row*256 + 0*64 + (lane>>4)*16);
          const bf16x8 a0 = *(const bf16x8*)(h0rd + off);
          #pragma unroll
          for (int q = 0; q < 4; ++q)
            acc[q] = __builtin_amdgcn_mfma_f32_16x16x32_bf16(a0, whh0f[q][0], zr[q], 0, 0, 0);
        }
        #pragma unroll
        for (int kt = 1; kt < 4; ++kt){
          int off = SWZ(row, row*256 + kt*64 + (lane>>4)*16);
          const bf16x8 a0 = *(const bf16x8*)(h0rd + off);
          #pragma unroll
          for (int q = 0; q < 4; ++q)
            acc[q] = __builtin_amdgcn_mfma_f32_16x16x32_bf16(a0, whh0f[q][kt], acc[q], 0, 0, 0);
        }
        {
          float hv[4];
          #pragma unroll
          for (int r = 0; r < 4; ++r){
            float iv = sigm(acc[0][r]), fv = sigm(acc[1][r]);
            float gv = tanh_f(acc[2][r]), ov = sigm(acc[3][r]);
            c0[r] = fv*c0[r] + iv*gv;
            hv[r] = ov * tanh_f(c0[r]);
          }
          unsigned int pk01 = cvtpk_bf16(hv[0], hv[1]);
          unsigned int pk23 = cvtpk_bf16(hv[2], hv[3]);
          *(unsigned short*)(h0wr + SWZ(rbase,   (rbase  )*256 + jcol*2)) = (unsigned short)pk01;
          *(unsigned short*)(h0wr + SWZ(rbase+1, (rbase+1)*256 + jcol*2)) = (unsigned short)(pk01 >> 16);
          *(unsigned short*)(h0wr + SWZ(rbase+2, (rbase+2)*256 + jcol*2)) = (unsigned short)pk23;
          *(unsigned short*)(h0wr + SWZ(rbase+3, (rbase+3)*256 + jcol*2)) = (unsigned short)(pk23 >> 16);
        }
        lgkm_barrier();
      }
    } else {
      // ---- seq arm: input is the scalar token; wc lives only here ----
      float wc[4];
      #pragma unroll
      for (int q = 0; q < 4; ++q) wc[q] = sWih0[128*q + jcol];
      // A(0): h[-1]=0
      {
        float g0[4][4];
        #pragma unroll
        for (int r = 0; r < 4; ++r){
          float sv = (float)sAll[(rbase + r)*64 + 0];
          #pragma unroll
          for (int q = 0; q < 4; ++q) g0[q][r] = fmaf(sv, wc[q], b0c[q]);
        }
        #pragma unroll
        for (int r = 0; r < 4; ++r){
          float iv = sigm(g0[0][r]);
          float gv = tanh_f(g0[2][r]);
          float ov = sigm(g0[3][r]);
          c0[r] = iv * gv;                 // f*c_prev = 0
          float h = ov * tanh_f(c0[r]);
          int row = rbase + r;
          *(unsigned short*)(h0base + 4096 + SWZ(row, row*256 + jcol*2)) = f2bf(h);  // h0[0] -> buf 1
        }
      }
      lgkm_barrier();    // barrier #1: h0[0] visible

      for (int t = 0; t < NSTEP-1; ++t){
        char* h0rd = h0base + ((t+1)&1)*4096;   // h0[t]
        char* h0wr = h0base + ((t  )&1)*4096;   // h0[t+1]
        f32x4 acc[4];
        float sv[4];
        #pragma unroll
        for (int r = 0; r < 4; ++r) sv[r] = (float)sAll[(rbase + r)*64 + t + 1];
        #pragma unroll
        for (int q = 0; q < 4; ++q){
          f32x4 a;
          #pragma unroll
          for (int r = 0; r < 4; ++r) a[r] = fmaf(sv[r], wc[q], b0c[q]);
          acc[q] = a;
        }
        #pragma unroll
        for (int kt = 0; kt < 4; ++kt){
          int row = lane & 15;
          int off = SWZ(row, row*256 + kt*64 + (lane>>4)*16);
          const bf16x8 a0 = *(const bf16x8*)(h0rd + off);
          #pragma unroll
          for (int q = 0; q < 4; ++q)
            acc[q] = __builtin_amdgcn_mfma_f32_16x16x32_bf16(a0, whh0f[q][kt], acc[q], 0, 0, 0);
        }
        {
          float hv[4];
          #pragma unroll
          for (int r = 0; r < 4; ++r){
            float iv = sigm(acc[0][r]), fv = sigm(acc[1][r]);
            float gv = tanh_f(acc[2][r]), ov = sigm(acc[3][r]);
            c0[r] = fv*c0[r] + iv*gv;
            hv[r] = ov * tanh_f(c0[r]);
          }
          unsigned int pk01 = cvtpk_bf16(hv[0], hv[1]);
          unsigned int pk23 = cvtpk_bf16(hv[2], hv[3]);
          *(unsigned short*)(h0wr + SWZ(rbase,   (rbase  )*256 + jcol*2)) = (unsigned short)pk01;
          *(unsigned short*)(h0wr + SWZ(rbase+1, (rbase+1)*256 + jcol*2)) = (unsigned short)(pk01 >> 16);
          *(unsigned short*)(h0wr + SWZ(rbase+2, (rbase+2)*256 + jcol*2)) = (unsigned short)pk23;
          *(unsigned short*)(h0wr + SWZ(rbase+3, (rbase+3)*256 + jcol*2)) = (unsigned short)(pk23 >> 16);
        }
        lgkm_barrier();
      }
    }
    // L0 done: 64 barriers executed, matching L1's count before its epilogue.
  }
}

// out[b][e] = dot(hcat[b], clsW[e]) + clsb[e]; clsWT is [256][1024].
// R22: 512 threads (2 waves/SIMD), WPB=8, full 1024 events/block; hcat read
// as f32x4 per 4-j group (8 vector LDS reads per 4 j vs 32 scalar) -- same
// traffic and FMA count, 1/4 the LDS issue slots, 4-deep load pipeline.
__global__ __launch_bounds__(512, 2)
void cls_k(const float* __restrict__ hseq, const float* __restrict__ hq,
           const float* __restrict__ clsWT, const float* __restrict__ clsb,
           float* __restrict__ out)
{
  __shared__ __attribute__((aligned(16))) float hcat[WPB][2*NHID];   // 8 KB
  const int tid = threadIdx.x;          // 0..511
  const int w0 = blockIdx.x * WPB;
  for (int i = tid; i < WPB*2*NHID; i += 512){
    int w = i >> 8; int j = i & (2*NHID-1);
    hcat[w][j] = (j < NHID) ? hseq[(w0+w)*NHID + j] : hq[(w0+w)*NHID + (j - NHID)];
  }
  __syncthreads();
  float acc[2][WPB];
  #pragma unroll
  for (int p=0;p<2;++p)
    #pragma unroll
    for (int w=0;w<WPB;++w) acc[p][w] = 0.0f;
  for (int j4 = 0; j4 < (2*NHID)/4; ++j4){
    f32x4 hv4[WPB];
    #pragma unroll
    for (int w=0; w<WPB; ++w) hv4[w] = *(const f32x4*)&hcat[w][j4*4];
    #pragma unroll
    for (int jj = 0; jj < 4; ++jj){
      int j = j4*4 + jj;
      float wv0 = clsWT[j*NEVENT + tid];
      float wv1 = clsWT[j*NEVENT + tid + 512];
      #pragma unroll
      for (int w=0; w<WPB; ++w){
        float hv = hv4[w][jj];
        acc[0][w] = fmaf(hv, wv0, acc[0][w]);
        acc[1][w] = fmaf(hv, wv1, acc[1][w]);
      }
    }
  }
  float bb0 = clsb[tid];
  float bb1 = clsb[tid + 512];
  #pragma unroll
  for (int w=0;w<WPB;++w){
    out[(w0+w)*NEVENT + tid]       = acc[0][w] + bb0;
    out[(w0+w)*NEVENT + tid + 512] = acc[1][w] + bb1;
  }
}

extern "C" void kernel_launch(void* const* d_in, const int* in_sizes, int n_in,
                              void* d_out, int out_size, void* d_ws, size_t ws_size,
                              hipStream_t stream) {
  const int*   seqtok = (const int*)  d_in[0];
  const float* sWih0  = (const float*)d_in[1];
  const float* sWhh0  = (const float*)d_in[2];
  const float* sb0i   = (const float*)d_in[3];
  const float* sb0h   = (const float*)d_in[4];
  const float* sWih1  = (const float*)d_in[5];
  const float* sWhh1  = (const float*)d_in[6];
  const float* sb1i   = (const float*)d_in[7];
  const float* sb1h   = (const float*)d_in[8];
  const float* qWih0  = (const float*)d_in[9];
  const float* qWhh0  = (const float*)d_in[10];
  const float* qb0i   = (const float*)d_in[11];
  const float* qb0h   = (const float*)d_in[12];
  const float* qWih1  = (const float*)d_in[13];
  const float* qWhh1  = (const float*)d_in[14];
  const float* qb1i   = (const float*)d_in[15];
  const float* qb1h   = (const float*)d_in[16];
  const float* clsW   = (const float*)d_in[17];
  const float* clsb   = (const float*)d_in[18];

  float* ws = (float*)d_ws;
  float* qWqT  = ws;                    // 1024*512 = 524288
  float* clsWT = ws + 524288;           // 256*1024 = 262144
  float* hseq  = ws + 786432;           // 2048*128 = 262144
  float* hq    = ws + 1048576;          // 262144
  unsigned short* pk = (unsigned short*)(ws + 1310720);
  unsigned short* pWhh0_s = pk;             // 6 matrices x 65536 ushorts
  unsigned short* pWih1_s = pk + 65536;
  unsigned short* pWhh1_s = pk + 131072;
  unsigned short* pWhh0_q = pk + 196608;
  unsigned short* pWih1_q = pk + 262144;
  unsigned short* pWhh1_q = pk + 327680;

  prep_k<<<960, 256, 0, stream>>>(qWih0, qWqT, clsW, clsWT,
      sWhh0, sWih1, sWhh1, qWhh0, qWih1, qWhh1, pk);

  lstm_fused_k<<<256, 1024, 0, stream>>>(seqtok, sWih0,
      sb0i, sb0h, sb1i, sb1h, qb0i, qb0h, qb1i, qb1h,
      pWhh0_s, pWih1_s, pWhh1_s, pWhh0_q, pWih1_q, pWhh1_q,
      qWqT, hseq, hq);

  cls_k<<<NWINDOW/WPB, 512, 0, stream>>>(hseq, hq, clsWT, clsb, (float*)d_out);
}

// Round 14
// 195.031 us; speedup vs baseline: 1.0236x; 1.0236x over previous
//
#include <hip/hip_runtime.h>
#include <hip/hip_bf16.h>
#include <math.h>

#define NEVENT 1024
#define NSTEP 64
#define NWINDOW 2048
#define NHID 128
#define NG 512
#define WPB 8   // windows per block in cls_k

typedef __attribute__((ext_vector_type(8))) short bf16x8;
typedef __attribute__((ext_vector_type(4))) float f32x4;

__device__ __forceinline__ unsigned short f2bf(float f){
  unsigned int u = __float_as_uint(f);
  return (unsigned short)((u + 0x7FFFu + ((u >> 16) & 1u)) >> 16);
}
__device__ __forceinline__ float sigm(float x){
  return __builtin_amdgcn_rcpf(1.0f + __expf(-x));
}
__device__ __forceinline__ float tanh_f(float x){
  float e = __expf(2.0f * x);
  return 1.0f - 2.0f * __builtin_amdgcn_rcpf(e + 1.0f);
}
// lgkm-only barrier: LDS ordering without draining vmcnt (global gathers stay in flight)
__device__ __forceinline__ void lgkm_barrier(){
  asm volatile("s_waitcnt lgkmcnt(0)" ::: "memory");
  __builtin_amdgcn_s_barrier();
}
// packed f32x2 -> bf16x2, RNE (bit-identical to f2bf); dst[15:0]=bf16(a), dst[31:16]=bf16(b)
__device__ __forceinline__ unsigned int cvtpk_bf16(float a, float b){
  unsigned int r;
  asm("v_cvt_pk_bf16_f32 %0, %1, %2" : "=v"(r) : "v"(a), "v"(b));
  return r;
}
// swizzle byte offset within h tile: spread rows across 16B slots
#define SWZ(row, byte) ((byte) ^ (((row) & 7) << 4))

// merged prep kernel:
//  blocks [0,512):   LDS-tiled transpose qWih0 [512][1024] -> qWqT [1024][512]
//  blocks [512,768): LDS-tiled transpose clsW  [1024][256] -> clsWT [256][1024]
//  blocks [768,960): pack6 (six W [512][128] f32 -> bf16 MFMA B-fragments)
__global__ __launch_bounds__(256)
void prep_k(const float* __restrict__ qWih0, float* __restrict__ qWqT,
            const float* __restrict__ clsW,  float* __restrict__ clsWT,
            const float* __restrict__ s0, const float* __restrict__ s1,
            const float* __restrict__ s2, const float* __restrict__ s3,
            const float* __restrict__ s4, const float* __restrict__ s5,
            unsigned short* __restrict__ dst)
{
  const int b = blockIdx.x;
  if (b < 768){
    // ---- tiled transpose: out[c][r] = in[r][c], both sides coalesced ----
    const float* in; float* out; int R, C, bb;
    if (b < 512){ in = qWih0; out = qWqT; R = NG;     C = NEVENT; bb = b; }
    else        { in = clsW;  out = clsWT; R = NEVENT; C = 2*NHID; bb = b - 512; }
    __shared__ float tl[32][33];
    const int nbx = C >> 5;
    const int by = bb / nbx, bx = bb - by*nbx;
    const int tx = threadIdx.x & 31, ty = threadIdx.x >> 5;
    #pragma unroll
    for (int k = 0; k < 4; ++k){
      int r = by*32 + ty + k*8;
      tl[ty + k*8][tx] = in[r*C + bx*32 + tx];
    }
    __syncthreads();
    #pragma unroll
    for (int k = 0; k < 4; ++k){
      int r = bx*32 + ty + k*8;               // out row = original col
      out[r*R + by*32 + tx] = tl[tx][ty + k*8];
    }
  } else {
    // ---- pack6: frag (kt,n): lane holds B[k][col], col=16n+(lane&15),
    // k=32kt+8*(lane>>4)+j, j=0..7 ----
    const int bb = b - 768;
    const int g = bb >> 5;
    const int i = (bb & 31)*256 + threadIdx.x;   // [0, 8192)
    const float* src = (g==0)?s0:(g==1)?s1:(g==2)?s2:(g==3)?s3:(g==4)?s4:s5;
    unsigned short* d = dst + g*65536;
    const int lane = i & 63; const int n = (i >> 6) & 31; const int kt = i >> 11;
    const int col = 16*n + (lane & 15);
    const int k0  = 32*kt + 8*(lane >> 4);
    #pragma unroll
    for (int j = 0; j < 8; ++j)
      d[i*8 + j] = f2bf(src[col*128 + k0 + j]);
  }
}

// R23 lstm = R21 lstm VERBATIM (verified 166.8us). R22's C-in fold regressed
// it to 174us: persistent b1v[4] (+12 regs) and f32x4 zr lengthened live
// ranges -> more spill (WRITE 11.3->13.6MB). Sixth confirmation: only
// transient-shrinking changes help this kernel; any added persistent state
// spills. Structure: role-split (waves 0-7 = L1/phase-C, 8-15 = L0/phase-A),
// one lgkm barrier/step, JIT quant gather, cvt_pk h-stores everywhere.
// Tripwires: absmax == 1.9531e-3 exactly; WRITE ~11.3MB / FETCH ~14.9MB.
__global__ __launch_bounds__(1024) __attribute__((amdgpu_waves_per_eu(4, 4)))
void lstm_fused_k(const int* __restrict__ seqtok,
    const float* __restrict__ sWih0,
    const float* __restrict__ sb0i, const float* __restrict__ sb0h,
    const float* __restrict__ sb1i, const float* __restrict__ sb1h,
    const float* __restrict__ qb0i, const float* __restrict__ qb0h,
    const float* __restrict__ qb1i, const float* __restrict__ qb1h,
    const unsigned short* __restrict__ pWhh0_s, const unsigned short* __restrict__ pWih1_s,
    const unsigned short* __restrict__ pWhh1_s,
    const unsigned short* __restrict__ pWhh0_q, const unsigned short* __restrict__ pWih1_q,
    const unsigned short* __restrict__ pWhh1_q,
    const float* __restrict__ qWqT,    // [1024][512]
    float* __restrict__ hseq, float* __restrict__ hq)
{
  __shared__ uint4 wih1[8192];                                            // 128 KB
  __shared__ __attribute__((aligned(16))) unsigned short h0buf[2][2048];  // 2 x 4KB
  __shared__ __attribute__((aligned(16))) unsigned short h1buf[2][2048];
  __shared__ int sAll[16*64];                                             // 4KB

  const int tid  = threadIdx.x;
  const int lane = tid & 63;
  const int w    = tid >> 6;            // wave id 0..15
  const bool quant = (blockIdx.x >= 128);
  const int blk  = quant ? (int)blockIdx.x - 128 : (int)blockIdx.x;
  const int w0   = blk * 16;

  // ---- prologue staging (all 16 waves) ----
  const uint4* wsrc = (const uint4*)(quant ? pWih1_q : pWih1_s);
  for (int i = tid; i < 8192; i += 1024) wih1[i] = wsrc[i];
  sAll[tid] = seqtok[w0*64 + tid];                       // [16 win][64 t] contiguous
  for (int i = tid; i < 2048; i += 1024){ h0buf[0][i] = 0; h1buf[0][i] = 0; }

  const int rbase = 4*(lane >> 4);         // window row base (D-layout)
  char* const h0base = (char*)h0buf;
  char* const h1base = (char*)h1buf;

  __syncthreads();   // barrier #0: staged data ready

  if (w < 8){
    // ================= L1 role: layer-1, phase C(t) =================
    const int nw   = w;
    const int jcol = 16*nw + (lane & 15);
    const float* b1i = quant ? qb1i : sb1i; const float* b1h = quant ? qb1h : sb1h;
    float b1c[4];
    #pragma unroll
    for (int q = 0; q < 4; ++q){ int col = 128*q + jcol; b1c[q] = b1i[col] + b1h[col]; }
    const unsigned short* p1 = quant ? pWhh1_q : pWhh1_s;
    bf16x8 whh1f[4][4];
    #pragma unroll
    for (int q = 0; q < 4; ++q)
      #pragma unroll
      for (int kt = 0; kt < 4; ++kt)
        whh1f[q][kt] = *(const bf16x8*)(p1 + ((kt*32 + 8*q + nw)*64 + lane)*8);
    float c1[4] = {0,0,0,0};
    float* const houtp = quant ? hq : hseq;

    lgkm_barrier();    // barrier #1: pairs with L0's post-A(0) barrier -> h0[0] ready

    for (int t = 0; t < NSTEP-1; ++t){
      char* h0rd = h0base + ((t+1)&1)*4096;   // h0[t]
      char* h1rd = h1base + ((t  )&1)*4096;   // h1[t-1]
      char* h1wr = h1base + ((t+1)&1)*4096;   // h1[t]
      f32x4 acc[4];
      #pragma unroll
      for (int q = 0; q < 4; ++q){ f32x4 a; a[0]=b1c[q]; a[1]=b1c[q]; a[2]=b1c[q]; a[3]=b1c[q]; acc[q] = a; }
      #pragma unroll
      for (int kt = 0; kt < 4; ++kt){
        int row = lane & 15;
        int off = SWZ(row, row*256 + kt*64 + (lane>>4)*16);
        const bf16x8 a0 = *(const bf16x8*)(h0rd + off);
        const bf16x8 a1 = *(const bf16x8*)(h1rd + off);
        #pragma unroll
        for (int q = 0; q < 4; ++q){
          const bf16x8 wi = *(const bf16x8*)((const char*)wih1 + ((kt*32 + 8*q + nw)*64 + lane)*16);
          acc[q] = __builtin_amdgcn_mfma_f32_16x16x32_bf16(a0, wi,           acc[q], 0, 0, 0);
          acc[q] = __builtin_amdgcn_mfma_f32_16x16x32_bf16(a1, whh1f[q][kt], acc[q], 0, 0, 0);
        }
      }
      {
        float hv[4];
        #pragma unroll
        for (int r = 0; r < 4; ++r){
          float iv = sigm(acc[0][r]), fv = sigm(acc[1][r]);
          float gv = tanh_f(acc[2][r]), ov = sigm(acc[3][r]);
          c1[r] = fv*c1[r] + iv*gv;
          hv[r] = ov * tanh_f(c1[r]);
        }
        unsigned int pk01 = cvtpk_bf16(hv[0], hv[1]);
        unsigned int pk23 = cvtpk_bf16(hv[2], hv[3]);
        *(unsigned short*)(h1wr + SWZ(rbase,   (rbase  )*256 + jcol*2)) = (unsigned short)pk01;
        *(unsigned short*)(h1wr + SWZ(rbase+1, (rbase+1)*256 + jcol*2)) = (unsigned short)(pk01 >> 16);
        *(unsigned short*)(h1wr + SWZ(rbase+2, (rbase+2)*256 + jcol*2)) = (unsigned short)pk23;
        *(unsigned short*)(h1wr + SWZ(rbase+3, (rbase+3)*256 + jcol*2)) = (unsigned short)(pk23 >> 16);
      }
      lgkm_barrier();
    }

    // ---- epilogue C(63): write global output only (L0 waves already done) ----
    {
      char* h0rd = h0base + 0*4096;           // h0[63] -> buf (63+1)&1 = 0
      char* h1rd = h1base + 1*4096;           // h1[62] -> buf 63&1 = 1
      f32x4 acc[4];
      #pragma unroll
      for (int q = 0; q < 4; ++q){ f32x4 a; a[0]=b1c[q]; a[1]=b1c[q]; a[2]=b1c[q]; a[3]=b1c[q]; acc[q] = a; }
      #pragma unroll
      for (int kt = 0; kt < 4; ++kt){
        int row = lane & 15;
        int off = SWZ(row, row*256 + kt*64 + (lane>>4)*16);
        const bf16x8 a0 = *(const bf16x8*)(h0rd + off);
        const bf16x8 a1 = *(const bf16x8*)(h1rd + off);
        #pragma unroll
        for (int q = 0; q < 4; ++q){
          const bf16x8 wi = *(const bf16x8*)((const char*)wih1 + ((kt*32 + 8*q + nw)*64 + lane)*16);
          acc[q] = __builtin_amdgcn_mfma_f32_16x16x32_bf16(a0, wi,           acc[q], 0, 0, 0);
          acc[q] = __builtin_amdgcn_mfma_f32_16x16x32_bf16(a1, whh1f[q][kt], acc[q], 0, 0, 0);
        }
      }
      #pragma unroll
      for (int r = 0; r < 4; ++r){
        float iv = sigm(acc[0][r]), fv = sigm(acc[1][r]);
        float gv = tanh_f(acc[2][r]), ov = sigm(acc[3][r]);
        c1[r] = fv*c1[r] + iv*gv;
        float h = ov * tanh_f(c1[r]);
        int row = rbase + r;
        houtp[(w0 + row)*128 + jcol] = h;
      }
    }
  } else {
    // ================= L0 role: layer-0, phase A(t+1) =================
    const int nw   = w - 8;
    const int jcol = 16*nw + (lane & 15);
    const float* b0i = quant ? qb0i : sb0i; const float* b0h = quant ? qb0h : sb0h;
    float b0c[4];
    #pragma unroll
    for (int q = 0; q < 4; ++q){
      int col = 128*q + jcol;
      b0c[q] = b0i[col] + b0h[col];
    }
    const unsigned short* p0 = quant ? pWhh0_q : pWhh0_s;
    bf16x8 whh0f[4][4];
    #pragma unroll
    for (int q = 0; q < 4; ++q)
      #pragma unroll
      for (int kt = 0; kt < 4; ++kt)
        whh0f[q][kt] = *(const bf16x8*)(p0 + ((kt*32 + 8*q + nw)*64 + lane)*8);

    float c0[4] = {0,0,0,0};

    if (quant){
      // ---- quant arm: R15 structure; h-store via cvt_pk (RNE-exact) ----
      float zr[4][4];
      #pragma unroll
      for (int q = 0; q < 4; ++q)
        #pragma unroll
        for (int r = 0; r < 4; ++r) zr[q][r] = b0c[q];
      // A(0): h[-1]=0; gather g(s_0) in place
      {
        float gvv[4][4];                // [q][r] transient
        #pragma unroll
        for (int r = 0; r < 4; ++r){
          int s = sAll[(rbase + r)*64 + 0];
          const float* gp = qWqT + s*512 + jcol;
          #pragma unroll
          for (int q = 0; q < 4; ++q) gvv[q][r] = gp[128*q];
        }
        float g0[4][4];
        #pragma unroll
        for (int q = 0; q < 4; ++q)
          #pragma unroll
          for (int r = 0; r < 4; ++r){ zr[q][r] += gvv[q][r]; g0[q][r] = zr[q][r]; }
        #pragma unroll
        for (int r = 0; r < 4; ++r){
          float iv = sigm(g0[0][r]);
          float gv = tanh_f(g0[2][r]);
          float ov = sigm(g0[3][r]);
          c0[r] = iv * gv;                 // f*c_prev = 0
          float h = ov * tanh_f(c0[r]);
          int row = rbase + r;
          *(unsigned short*)(h0base + 4096 + SWZ(row, row*256 + jcol*2)) = f2bf(h);  // h0[0] -> buf 1
        }
      }
      lgkm_barrier();    // barrier #1: h0[0] visible

      for (int t = 0; t < NSTEP-1; ++t){
        char* h0rd = h0base + ((t+1)&1)*4096;   // h0[t]
        char* h0wr = h0base + ((t  )&1)*4096;   // h0[t+1]
        // JIT gather g(s_{t+1}) -- issued first, consumed at acc init below;
        // latency hides in L0's matrix-pipe slack vs the L1 waves.
        float gvv[4][4];                // [q][r] transient
        #pragma unroll
        for (int r = 0; r < 4; ++r){
          int s = sAll[(rbase + r)*64 + t + 1];
          const float* gp = qWqT + s*512 + jcol;
          #pragma unroll
          for (int q = 0; q < 4; ++q) gvv[q][r] = gp[128*q];
        }
        f32x4 acc[4];
        #pragma unroll
        for (int q = 0; q < 4; ++q){
          f32x4 a;
          #pragma unroll
          for (int r = 0; r < 4; ++r){ zr[q][r] += gvv[q][r]; a[r] = zr[q][r]; }
          acc[q] = a;
        }
        #pragma unroll
        for (int kt = 0; kt < 4; ++kt){
          int row = lane & 15;
          int off = SWZ(row, row*256 + kt*64 + (lane>>4)*16);
          const bf16x8 a0 = *(const bf16x8*)(h0rd + off);
          #pragma unroll
          for (int q = 0; q < 4; ++q)
            acc[q] = __builtin_amdgcn_mfma_f32_16x16x32_bf16(a0, whh0f[q][kt], acc[q], 0, 0, 0);
        }
        {
          float hv[4];
          #pragma unroll
          for (int r = 0; r < 4; ++r){
            float iv = sigm(acc[0][r]), fv = sigm(acc[1][r]);
            float gv = tanh_f(acc[2][r]), ov = sigm(acc[3][r]);
            c0[r] = fv*c0[r] + iv*gv;
            hv[r] = ov * tanh_f(c0[r]);
          }
          unsigned int pk01 = cvtpk_bf16(hv[0], hv[1]);
          unsigned int pk23 = cvtpk_bf16(hv[2], hv[3]);
          *(unsigned short*)(h0wr + SWZ(rbase,   (rbase  )*256 + jcol*2)) = (unsigned short)pk01;
          *(unsigned short*)(h0wr + SWZ(rbase+1, (rbase+1)*256 + jcol*2)) = (unsigned short)(pk01 >> 16);
          *(unsigned short*)(h0wr + SWZ(rbase+2, (rbase+2)*256 + jcol*2)) = (unsigned short)pk23;
          *(unsigned short*)(h0wr + SWZ(rbase+3, (rbase+3)*256 + jcol*2)) = (unsigned short)(pk23 >> 16);
        }
        lgkm_barrier();
      }
    } else {
      // ---- seq arm: input is the scalar token; wc lives only here ----
      float wc[4];
      #pragma unroll
      for (int q = 0; q < 4; ++q) wc[q] = sWih0[128*q + jcol];
      // A(0): h[-1]=0
      {
        float g0[4][4];
        #pragma unroll
        for (int r = 0; r < 4; ++r){
          float sv = (float)sAll[(rbase + r)*64 + 0];
          #pragma unroll
          for (int q = 0; q < 4; ++q) g0[q][r] = fmaf(sv, wc[q], b0c[q]);
        }
        #pragma unroll
        for (int r = 0; r < 4; ++r){
          float iv = sigm(g0[0][r]);
          float gv = tanh_f(g0[2][r]);
          float ov = sigm(g0[3][r]);
          c0[r] = iv * gv;                 // f*c_prev = 0
          float h = ov * tanh_f(c0[r]);
          int row = rbase + r;
          *(unsigned short*)(h0base + 4096 + SWZ(row, row*256 + jcol*2)) = f2bf(h);  // h0[0] -> buf 1
        }
      }
      lgkm_barrier();    // barrier #1: h0[0] visible

      for (int t = 0; t < NSTEP-1; ++t){
        char* h0rd = h0base + ((t+1)&1)*4096;   // h0[t]
        char* h0wr = h0base + ((t  )&1)*4096;   // h0[t+1]
        f32x4 acc[4];
        float sv[4];
        #pragma unroll
        for (int r = 0; r < 4; ++r) sv[r] = (float)sAll[(rbase + r)*64 + t + 1];
        #pragma unroll
        for (int q = 0; q < 4; ++q){
          f32x4 a;
          #pragma unroll
          for (int r = 0; r < 4; ++r) a[r] = fmaf(sv[r], wc[q], b0c[q]);
          acc[q] = a;
        }
        #pragma unroll
        for (int kt = 0; kt < 4; ++kt){
          int row = lane & 15;
          int off = SWZ(row, row*256 + kt*64 + (lane>>4)*16);
          const bf16x8 a0 = *(const bf16x8*)(h0rd + off);
          #pragma unroll
          for (int q = 0; q < 4; ++q)
            acc[q] = __builtin_amdgcn_mfma_f32_16x16x32_bf16(a0, whh0f[q][kt], acc[q], 0, 0, 0);
        }
        {
          float hv[4];
          #pragma unroll
          for (int r = 0; r < 4; ++r){
            float iv = sigm(acc[0][r]), fv = sigm(acc[1][r]);
            float gv = tanh_f(acc[2][r]), ov = sigm(acc[3][r]);
            c0[r] = fv*c0[r] + iv*gv;
            hv[r] = ov * tanh_f(c0[r]);
          }
          unsigned int pk01 = cvtpk_bf16(hv[0], hv[1]);
          unsigned int pk23 = cvtpk_bf16(hv[2], hv[3]);
          *(unsigned short*)(h0wr + SWZ(rbase,   (rbase  )*256 + jcol*2)) = (unsigned short)pk01;
          *(unsigned short*)(h0wr + SWZ(rbase+1, (rbase+1)*256 + jcol*2)) = (unsigned short)(pk01 >> 16);
          *(unsigned short*)(h0wr + SWZ(rbase+2, (rbase+2)*256 + jcol*2)) = (unsigned short)pk23;
          *(unsigned short*)(h0wr + SWZ(rbase+3, (rbase+3)*256 + jcol*2)) = (unsigned short)(pk23 >> 16);
        }
        lgkm_barrier();
      }
    }
    // L0 done: 64 barriers executed, matching L1's count before its epilogue.
  }
}

// out[b][e] = dot(hcat[b], clsW[e]) + clsb[e]; clsWT is [256][1024].
// R23 cls = R22 cls VERBATIM (verified non-lstm 25.5us): 512 threads
// (2 waves/SIMD), WPB=8, full 1024 events/block; hcat read as f32x4 per
// 4-j group -- same traffic and FMA count, 1/4 the LDS issue slots.
__global__ __launch_bounds__(512, 2)
void cls_k(const float* __restrict__ hseq, const float* __restrict__ hq,
           const float* __restrict__ clsWT, const float* __restrict__ clsb,
           float* __restrict__ out)
{
  __shared__ __attribute__((aligned(16))) float hcat[WPB][2*NHID];   // 8 KB
  const int tid = threadIdx.x;          // 0..511
  const int w0 = blockIdx.x * WPB;
  for (int i = tid; i < WPB*2*NHID; i += 512){
    int w = i >> 8; int j = i & (2*NHID-1);
    hcat[w][j] = (j < NHID) ? hseq[(w0+w)*NHID + j] : hq[(w0+w)*NHID + (j - NHID)];
  }
  __syncthreads();
  float acc[2][WPB];
  #pragma unroll
  for (int p=0;p<2;++p)
    #pragma unroll
    for (int w=0;w<WPB;++w) acc[p][w] = 0.0f;
  for (int j4 = 0; j4 < (2*NHID)/4; ++j4){
    f32x4 hv4[WPB];
    #pragma unroll
    for (int w=0; w<WPB; ++w) hv4[w] = *(const f32x4*)&hcat[w][j4*4];
    #pragma unroll
    for (int jj = 0; jj < 4; ++jj){
      int j = j4*4 + jj;
      float wv0 = clsWT[j*NEVENT + tid];
      float wv1 = clsWT[j*NEVENT + tid + 512];
      #pragma unroll
      for (int w=0; w<WPB; ++w){
        float hv = hv4[w][jj];
        acc[0][w] = fmaf(hv, wv0, acc[0][w]);
        acc[1][w] = fmaf(hv, wv1, acc[1][w]);
      }
    }
  }
  float bb0 = clsb[tid];
  float bb1 = clsb[tid + 512];
  #pragma unroll
  for (int w=0;w<WPB;++w){
    out[(w0+w)*NEVENT + tid]       = acc[0][w] + bb0;
    out[(w0+w)*NEVENT + tid + 512] = acc[1][w] + bb1;
  }
}

extern "C" void kernel_launch(void* const* d_in, const int* in_sizes, int n_in,
                              void* d_out, int out_size, void* d_ws, size_t ws_size,
                              hipStream_t stream) {
  const int*   seqtok = (const int*)  d_in[0];
  const float* sWih0  = (const float*)d_in[1];
  const float* sWhh0  = (const float*)d_in[2];
  const float* sb0i   = (const float*)d_in[3];
  const float* sb0h   = (const float*)d_in[4];
  const float* sWih1  = (const float*)d_in[5];
  const float* sWhh1  = (const float*)d_in[6];
  const float* sb1i   = (const float*)d_in[7];
  const float* sb1h   = (const float*)d_in[8];
  const float* qWih0  = (const float*)d_in[9];
  const float* qWhh0  = (const float*)d_in[10];
  const float* qb0i   = (const float*)d_in[11];
  const float* qb0h   = (const float*)d_in[12];
  const float* qWih1  = (const float*)d_in[13];
  const float* qWhh1  = (const float*)d_in[14];
  const float* qb1i   = (const float*)d_in[15];
  const float* qb1h   = (const float*)d_in[16];
  const float* clsW   = (const float*)d_in[17];
  const float* clsb   = (const float*)d_in[18];

  float* ws = (float*)d_ws;
  float* qWqT  = ws;                    // 1024*512 = 524288
  float* clsWT = ws + 524288;           // 256*1024 = 262144
  float* hseq  = ws + 786432;           // 2048*128 = 262144
  float* hq    = ws + 1048576;          // 262144
  unsigned short* pk = (unsigned short*)(ws + 1310720);
  unsigned short* pWhh0_s = pk;             // 6 matrices x 65536 ushorts
  unsigned short* pWih1_s = pk + 65536;
  unsigned short* pWhh1_s = pk + 131072;
  unsigned short* pWhh0_q = pk + 196608;
  unsigned short* pWih1_q = pk + 262144;
  unsigned short* pWhh1_q = pk + 327680;

  prep_k<<<960, 256, 0, stream>>>(qWih0, qWqT, clsW, clsWT,
      sWhh0, sWih1, sWhh1, qWhh0, qWih1, qWhh1, pk);

  lstm_fused_k<<<256, 1024, 0, stream>>>(seqtok, sWih0,
      sb0i, sb0h, sb1i, sb1h, qb0i, qb0h, qb1i, qb1h,
      pWhh0_s, pWih1_s, pWhh1_s, pWhh0_q, pWih1_q, pWhh1_q,
      qWqT, hseq, hq);

  cls_k<<<NWINDOW/WPB, 512, 0, stream>>>(hseq, hq, clsWT, clsb, (float*)d_out);
}

// Round 15
// 194.796 us; speedup vs baseline: 1.0248x; 1.0012x over previous
//
#include <hip/hip_runtime.h>
#include <hip/hip_bf16.h>
#include <math.h>

#define NEVENT 1024
#define NSTEP 64
#define NWINDOW 2048
#define NHID 128
#define NG 512
#define WPB 8   // windows per block in cls_k

typedef __attribute__((ext_vector_type(8))) short bf16x8;
typedef __attribute__((ext_vector_type(4))) float f32x4;

__device__ __forceinline__ unsigned short f2bf(float f){
  unsigned int u = __float_as_uint(f);
  return (unsigned short)((u + 0x7FFFu + ((u >> 16) & 1u)) >> 16);
}
__device__ __forceinline__ float sigm(float x){
  return __builtin_amdgcn_rcpf(1.0f + __expf(-x));
}
__device__ __forceinline__ float tanh_f(float x){
  float e = __expf(2.0f * x);
  return 1.0f - 2.0f * __builtin_amdgcn_rcpf(e + 1.0f);
}
// lgkm-only barrier: LDS ordering without draining vmcnt (global gathers stay in flight)
__device__ __forceinline__ void lgkm_barrier(){
  asm volatile("s_waitcnt lgkmcnt(0)" ::: "memory");
  __builtin_amdgcn_s_barrier();
}
// packed f32x2 -> bf16x2, RNE (bit-identical to f2bf); dst[15:0]=bf16(a), dst[31:16]=bf16(b)
__device__ __forceinline__ unsigned int cvtpk_bf16(float a, float b){
  unsigned int r;
  asm("v_cvt_pk_bf16_f32 %0, %1, %2" : "=v"(r) : "v"(a), "v"(b));
  return r;
}
// swizzle byte offset within h tile: spread rows across 16B slots
#define SWZ(row, byte) ((byte) ^ (((row) & 7) << 4))

// merged prep kernel:
//  blocks [0,512):   LDS-tiled transpose qWih0 [512][1024] -> qWqT [1024][512]
//  blocks [512,768): LDS-tiled transpose clsW  [1024][256] -> clsWT [256][1024]
//  blocks [768,960): pack6 (six W [512][128] f32 -> bf16 MFMA B-fragments)
__global__ __launch_bounds__(256)
void prep_k(const float* __restrict__ qWih0, float* __restrict__ qWqT,
            const float* __restrict__ clsW,  float* __restrict__ clsWT,
            const float* __restrict__ s0, const float* __restrict__ s1,
            const float* __restrict__ s2, const float* __restrict__ s3,
            const float* __restrict__ s4, const float* __restrict__ s5,
            unsigned short* __restrict__ dst)
{
  const int b = blockIdx.x;
  if (b < 768){
    // ---- tiled transpose: out[c][r] = in[r][c], both sides coalesced ----
    const float* in; float* out; int R, C, bb;
    if (b < 512){ in = qWih0; out = qWqT; R = NG;     C = NEVENT; bb = b; }
    else        { in = clsW;  out = clsWT; R = NEVENT; C = 2*NHID; bb = b - 512; }
    __shared__ float tl[32][33];
    const int nbx = C >> 5;
    const int by = bb / nbx, bx = bb - by*nbx;
    const int tx = threadIdx.x & 31, ty = threadIdx.x >> 5;
    #pragma unroll
    for (int k = 0; k < 4; ++k){
      int r = by*32 + ty + k*8;
      tl[ty + k*8][tx] = in[r*C + bx*32 + tx];
    }
    __syncthreads();
    #pragma unroll
    for (int k = 0; k < 4; ++k){
      int r = bx*32 + ty + k*8;               // out row = original col
      out[r*R + by*32 + tx] = tl[tx][ty + k*8];
    }
  } else {
    // ---- pack6: frag (kt,n): lane holds B[k][col], col=16n+(lane&15),
    // k=32kt+8*(lane>>4)+j, j=0..7 ----
    const int bb = b - 768;
    const int g = bb >> 5;
    const int i = (bb & 31)*256 + threadIdx.x;   // [0, 8192)
    const float* src = (g==0)?s0:(g==1)?s1:(g==2)?s2:(g==3)?s3:(g==4)?s4:s5;
    unsigned short* d = dst + g*65536;
    const int lane = i & 63; const int n = (i >> 6) & 31; const int kt = i >> 11;
    const int col = 16*n + (lane & 15);
    const int k0  = 32*kt + 8*(lane >> 4);
    #pragma unroll
    for (int j = 0; j < 8; ++j)
      d[i*8 + j] = f2bf(src[col*128 + k0 + j]);
  }
}

// R24 lstm = R23 lstm (verified 166.8-167.4us) + unroll(disable) on the L0
// t-loops. Hypothesis: the compiler unrolls the quant t-loop x2 to
// constant-fold the ((t+1)&1) buffer parity, doubling the gather/zr live
// window -> the residual ~9MB scratch spill whose readback stalls are on the
// quant critical path (R13->R15 correlation: every MB of spill removed bought
// wall time). Pragma is bit-exact; null if the compiler wasn't unrolling.
// Tripwires: absmax == 1.9531e-3 exactly; WRITE <= 11.3MB (any rise => revert).
__global__ __launch_bounds__(1024) __attribute__((amdgpu_waves_per_eu(4, 4)))
void lstm_fused_k(const int* __restrict__ seqtok,
    const float* __restrict__ sWih0,
    const float* __restrict__ sb0i, const float* __restrict__ sb0h,
    const float* __restrict__ sb1i, const float* __restrict__ sb1h,
    const float* __restrict__ qb0i, const float* __restrict__ qb0h,
    const float* __restrict__ qb1i, const float* __restrict__ qb1h,
    const unsigned short* __restrict__ pWhh0_s, const unsigned short* __restrict__ pWih1_s,
    const unsigned short* __restrict__ pWhh1_s,
    const unsigned short* __restrict__ pWhh0_q, const unsigned short* __restrict__ pWih1_q,
    const unsigned short* __restrict__ pWhh1_q,
    const float* __restrict__ qWqT,    // [1024][512]
    float* __restrict__ hseq, float* __restrict__ hq)
{
  __shared__ uint4 wih1[8192];                                            // 128 KB
  __shared__ __attribute__((aligned(16))) unsigned short h0buf[2][2048];  // 2 x 4KB
  __shared__ __attribute__((aligned(16))) unsigned short h1buf[2][2048];
  __shared__ int sAll[16*64];                                             // 4KB

  const int tid  = threadIdx.x;
  const int lane = tid & 63;
  const int w    = tid >> 6;            // wave id 0..15
  const bool quant = (blockIdx.x >= 128);
  const int blk  = quant ? (int)blockIdx.x - 128 : (int)blockIdx.x;
  const int w0   = blk * 16;

  // ---- prologue staging (all 16 waves) ----
  const uint4* wsrc = (const uint4*)(quant ? pWih1_q : pWih1_s);
  for (int i = tid; i < 8192; i += 1024) wih1[i] = wsrc[i];
  sAll[tid] = seqtok[w0*64 + tid];                       // [16 win][64 t] contiguous
  for (int i = tid; i < 2048; i += 1024){ h0buf[0][i] = 0; h1buf[0][i] = 0; }

  const int rbase = 4*(lane >> 4);         // window row base (D-layout)
  char* const h0base = (char*)h0buf;
  char* const h1base = (char*)h1buf;

  __syncthreads();   // barrier #0: staged data ready

  if (w < 8){
    // ================= L1 role: layer-1, phase C(t) =================
    const int nw   = w;
    const int jcol = 16*nw + (lane & 15);
    const float* b1i = quant ? qb1i : sb1i; const float* b1h = quant ? qb1h : sb1h;
    float b1c[4];
    #pragma unroll
    for (int q = 0; q < 4; ++q){ int col = 128*q + jcol; b1c[q] = b1i[col] + b1h[col]; }
    const unsigned short* p1 = quant ? pWhh1_q : pWhh1_s;
    bf16x8 whh1f[4][4];
    #pragma unroll
    for (int q = 0; q < 4; ++q)
      #pragma unroll
      for (int kt = 0; kt < 4; ++kt)
        whh1f[q][kt] = *(const bf16x8*)(p1 + ((kt*32 + 8*q + nw)*64 + lane)*8);
    float c1[4] = {0,0,0,0};
    float* const houtp = quant ? hq : hseq;

    lgkm_barrier();    // barrier #1: pairs with L0's post-A(0) barrier -> h0[0] ready

    for (int t = 0; t < NSTEP-1; ++t){
      char* h0rd = h0base + ((t+1)&1)*4096;   // h0[t]
      char* h1rd = h1base + ((t  )&1)*4096;   // h1[t-1]
      char* h1wr = h1base + ((t+1)&1)*4096;   // h1[t]
      f32x4 acc[4];
      #pragma unroll
      for (int q = 0; q < 4; ++q){ f32x4 a; a[0]=b1c[q]; a[1]=b1c[q]; a[2]=b1c[q]; a[3]=b1c[q]; acc[q] = a; }
      #pragma unroll
      for (int kt = 0; kt < 4; ++kt){
        int row = lane & 15;
        int off = SWZ(row, row*256 + kt*64 + (lane>>4)*16);
        const bf16x8 a0 = *(const bf16x8*)(h0rd + off);
        const bf16x8 a1 = *(const bf16x8*)(h1rd + off);
        #pragma unroll
        for (int q = 0; q < 4; ++q){
          const bf16x8 wi = *(const bf16x8*)((const char*)wih1 + ((kt*32 + 8*q + nw)*64 + lane)*16);
          acc[q] = __builtin_amdgcn_mfma_f32_16x16x32_bf16(a0, wi,           acc[q], 0, 0, 0);
          acc[q] = __builtin_amdgcn_mfma_f32_16x16x32_bf16(a1, whh1f[q][kt], acc[q], 0, 0, 0);
        }
      }
      {
        float hv[4];
        #pragma unroll
        for (int r = 0; r < 4; ++r){
          float iv = sigm(acc[0][r]), fv = sigm(acc[1][r]);
          float gv = tanh_f(acc[2][r]), ov = sigm(acc[3][r]);
          c1[r] = fv*c1[r] + iv*gv;
          hv[r] = ov * tanh_f(c1[r]);
        }
        unsigned int pk01 = cvtpk_bf16(hv[0], hv[1]);
        unsigned int pk23 = cvtpk_bf16(hv[2], hv[3]);
        *(unsigned short*)(h1wr + SWZ(rbase,   (rbase  )*256 + jcol*2)) = (unsigned short)pk01;
        *(unsigned short*)(h1wr + SWZ(rbase+1, (rbase+1)*256 + jcol*2)) = (unsigned short)(pk01 >> 16);
        *(unsigned short*)(h1wr + SWZ(rbase+2, (rbase+2)*256 + jcol*2)) = (unsigned short)pk23;
        *(unsigned short*)(h1wr + SWZ(rbase+3, (rbase+3)*256 + jcol*2)) = (unsigned short)(pk23 >> 16);
      }
      lgkm_barrier();
    }

    // ---- epilogue C(63): write global output only (L0 waves already done) ----
    {
      char* h0rd = h0base + 0*4096;           // h0[63] -> buf (63+1)&1 = 0
      char* h1rd = h1base + 1*4096;           // h1[62] -> buf 63&1 = 1
      f32x4 acc[4];
      #pragma unroll
      for (int q = 0; q < 4; ++q){ f32x4 a; a[0]=b1c[q]; a[1]=b1c[q]; a[2]=b1c[q]; a[3]=b1c[q]; acc[q] = a; }
      #pragma unroll
      for (int kt = 0; kt < 4; ++kt){
        int row = lane & 15;
        int off = SWZ(row, row*256 + kt*64 + (lane>>4)*16);
        const bf16x8 a0 = *(const bf16x8*)(h0rd + off);
        const bf16x8 a1 = *(const bf16x8*)(h1rd + off);
        #pragma unroll
        for (int q = 0; q < 4; ++q){
          const bf16x8 wi = *(const bf16x8*)((const char*)wih1 + ((kt*32 + 8*q + nw)*64 + lane)*16);
          acc[q] = __builtin_amdgcn_mfma_f32_16x16x32_bf16(a0, wi,           acc[q], 0, 0, 0);
          acc[q] = __builtin_amdgcn_mfma_f32_16x16x32_bf16(a1, whh1f[q][kt], acc[q], 0, 0, 0);
        }
      }
      #pragma unroll
      for (int r = 0; r < 4; ++r){
        float iv = sigm(acc[0][r]), fv = sigm(acc[1][r]);
        float gv = tanh_f(acc[2][r]), ov = sigm(acc[3][r]);
        c1[r] = fv*c1[r] + iv*gv;
        float h = ov * tanh_f(c1[r]);
        int row = rbase + r;
        houtp[(w0 + row)*128 + jcol] = h;
      }
    }
  } else {
    // ================= L0 role: layer-0, phase A(t+1) =================
    const int nw   = w - 8;
    const int jcol = 16*nw + (lane & 15);
    const float* b0i = quant ? qb0i : sb0i; const float* b0h = quant ? qb0h : sb0h;
    float b0c[4];
    #pragma unroll
    for (int q = 0; q < 4; ++q){
      int col = 128*q + jcol;
      b0c[q] = b0i[col] + b0h[col];
    }
    const unsigned short* p0 = quant ? pWhh0_q : pWhh0_s;
    bf16x8 whh0f[4][4];
    #pragma unroll
    for (int q = 0; q < 4; ++q)
      #pragma unroll
      for (int kt = 0; kt < 4; ++kt)
        whh0f[q][kt] = *(const bf16x8*)(p0 + ((kt*32 + 8*q + nw)*64 + lane)*8);

    float c0[4] = {0,0,0,0};

    if (quant){
      // ---- quant arm: R15 structure; h-store via cvt_pk (RNE-exact) ----
      float zr[4][4];
      #pragma unroll
      for (int q = 0; q < 4; ++q)
        #pragma unroll
        for (int r = 0; r < 4; ++r) zr[q][r] = b0c[q];
      // A(0): h[-1]=0; gather g(s_0) in place
      {
        float gvv[4][4];                // [q][r] transient
        #pragma unroll
        for (int r = 0; r < 4; ++r){
          int s = sAll[(rbase + r)*64 + 0];
          const float* gp = qWqT + s*512 + jcol;
          #pragma unroll
          for (int q = 0; q < 4; ++q) gvv[q][r] = gp[128*q];
        }
        float g0[4][4];
        #pragma unroll
        for (int q = 0; q < 4; ++q)
          #pragma unroll
          for (int r = 0; r < 4; ++r){ zr[q][r] += gvv[q][r]; g0[q][r] = zr[q][r]; }
        #pragma unroll
        for (int r = 0; r < 4; ++r){
          float iv = sigm(g0[0][r]);
          float gv = tanh_f(g0[2][r]);
          float ov = sigm(g0[3][r]);
          c0[r] = iv * gv;                 // f*c_prev = 0
          float h = ov * tanh_f(c0[r]);
          int row = rbase + r;
          *(unsigned short*)(h0base + 4096 + SWZ(row, row*256 + jcol*2)) = f2bf(h);  // h0[0] -> buf 1
        }
      }
      lgkm_barrier();    // barrier #1: h0[0] visible

      #pragma clang loop unroll(disable)
      for (int t = 0; t < NSTEP-1; ++t){
        char* h0rd = h0base + ((t+1)&1)*4096;   // h0[t]
        char* h0wr = h0base + ((t  )&1)*4096;   // h0[t+1]
        // JIT gather g(s_{t+1}) -- issued first, consumed at acc init below;
        // latency hides in L0's matrix-pipe slack vs the L1 waves.
        float gvv[4][4];                // [q][r] transient
        #pragma unroll
        for (int r = 0; r < 4; ++r){
          int s = sAll[(rbase + r)*64 + t + 1];
          const float* gp = qWqT + s*512 + jcol;
          #pragma unroll
          for (int q = 0; q < 4; ++q) gvv[q][r] = gp[128*q];
        }
        f32x4 acc[4];
        #pragma unroll
        for (int q = 0; q < 4; ++q){
          f32x4 a;
          #pragma unroll
          for (int r = 0; r < 4; ++r){ zr[q][r] += gvv[q][r]; a[r] = zr[q][r]; }
          acc[q] = a;
        }
        #pragma unroll
        for (int kt = 0; kt < 4; ++kt){
          int row = lane & 15;
          int off = SWZ(row, row*256 + kt*64 + (lane>>4)*16);
          const bf16x8 a0 = *(const bf16x8*)(h0rd + off);
          #pragma unroll
          for (int q = 0; q < 4; ++q)
            acc[q] = __builtin_amdgcn_mfma_f32_16x16x32_bf16(a0, whh0f[q][kt], acc[q], 0, 0, 0);
        }
        {
          float hv[4];
          #pragma unroll
          for (int r = 0; r < 4; ++r){
            float iv = sigm(acc[0][r]), fv = sigm(acc[1][r]);
            float gv = tanh_f(acc[2][r]), ov = sigm(acc[3][r]);
            c0[r] = fv*c0[r] + iv*gv;
            hv[r] = ov * tanh_f(c0[r]);
          }
          unsigned int pk01 = cvtpk_bf16(hv[0], hv[1]);
          unsigned int pk23 = cvtpk_bf16(hv[2], hv[3]);
          *(unsigned short*)(h0wr + SWZ(rbase,   (rbase  )*256 + jcol*2)) = (unsigned short)pk01;
          *(unsigned short*)(h0wr + SWZ(rbase+1, (rbase+1)*256 + jcol*2)) = (unsigned short)(pk01 >> 16);
          *(unsigned short*)(h0wr + SWZ(rbase+2, (rbase+2)*256 + jcol*2)) = (unsigned short)pk23;
          *(unsigned short*)(h0wr + SWZ(rbase+3, (rbase+3)*256 + jcol*2)) = (unsigned short)(pk23 >> 16);
        }
        lgkm_barrier();
      }
    } else {
      // ---- seq arm: input is the scalar token; wc lives only here ----
      float wc[4];
      #pragma unroll
      for (int q = 0; q < 4; ++q) wc[q] = sWih0[128*q + jcol];
      // A(0): h[-1]=0
      {
        float g0[4][4];
        #pragma unroll
        for (int r = 0; r < 4; ++r){
          float sv = (float)sAll[(rbase + r)*64 + 0];
          #pragma unroll
          for (int q = 0; q < 4; ++q) g0[q][r] = fmaf(sv, wc[q], b0c[q]);
        }
        #pragma unroll
        for (int r = 0; r < 4; ++r){
          float iv = sigm(g0[0][r]);
          float gv = tanh_f(g0[2][r]);
          float ov = sigm(g0[3][r]);
          c0[r] = iv * gv;                 // f*c_prev = 0
          float h = ov * tanh_f(c0[r]);
          int row = rbase + r;
          *(unsigned short*)(h0base + 4096 + SWZ(row, row*256 + jcol*2)) = f2bf(h);  // h0[0] -> buf 1
        }
      }
      lgkm_barrier();    // barrier #1: h0[0] visible

      #pragma clang loop unroll(disable)
      for (int t = 0; t < NSTEP-1; ++t){
        char* h0rd = h0base + ((t+1)&1)*4096;   // h0[t]
        char* h0wr = h0base + ((t  )&1)*4096;   // h0[t+1]
        f32x4 acc[4];
        float sv[4];
        #pragma unroll
        for (int r = 0; r < 4; ++r) sv[r] = (float)sAll[(rbase + r)*64 + t + 1];
        #pragma unroll
        for (int q = 0; q < 4; ++q){
          f32x4 a;
          #pragma unroll
          for (int r = 0; r < 4; ++r) a[r] = fmaf(sv[r], wc[q], b0c[q]);
          acc[q] = a;
        }
        #pragma unroll
        for (int kt = 0; kt < 4; ++kt){
          int row = lane & 15;
          int off = SWZ(row, row*256 + kt*64 + (lane>>4)*16);
          const bf16x8 a0 = *(const bf16x8*)(h0rd + off);
          #pragma unroll
          for (int q = 0; q < 4; ++q)
            acc[q] = __builtin_amdgcn_mfma_f32_16x16x32_bf16(a0, whh0f[q][kt], acc[q], 0, 0, 0);
        }
        {
          float hv[4];
          #pragma unroll
          for (int r = 0; r < 4; ++r){
            float iv = sigm(acc[0][r]), fv = sigm(acc[1][r]);
            float gv = tanh_f(acc[2][r]), ov = sigm(acc[3][r]);
            c0[r] = fv*c0[r] + iv*gv;
            hv[r] = ov * tanh_f(c0[r]);
          }
          unsigned int pk01 = cvtpk_bf16(hv[0], hv[1]);
          unsigned int pk23 = cvtpk_bf16(hv[2], hv[3]);
          *(unsigned short*)(h0wr + SWZ(rbase,   (rbase  )*256 + jcol*2)) = (unsigned short)pk01;
          *(unsigned short*)(h0wr + SWZ(rbase+1, (rbase+1)*256 + jcol*2)) = (unsigned short)(pk01 >> 16);
          *(unsigned short*)(h0wr + SWZ(rbase+2, (rbase+2)*256 + jcol*2)) = (unsigned short)pk23;
          *(unsigned short*)(h0wr + SWZ(rbase+3, (rbase+3)*256 + jcol*2)) = (unsigned short)(pk23 >> 16);
        }
        lgkm_barrier();
      }
    }
    // L0 done: 64 barriers executed, matching L1's count before its epilogue.
  }
}

// out[b][e] = dot(hcat[b], clsW[e]) + clsb[e]; clsWT is [256][1024].
// R24 cls = R22/R23 cls VERBATIM: 512 threads (2 waves/SIMD), WPB=8, full
// 1024 events/block; hcat read as f32x4 per 4-j group.
__global__ __launch_bounds__(512, 2)
void cls_k(const float* __restrict__ hseq, const float* __restrict__ hq,
           const float* __restrict__ clsWT, const float* __restrict__ clsb,
           float* __restrict__ out)
{
  __shared__ __attribute__((aligned(16))) float hcat[WPB][2*NHID];   // 8 KB
  const int tid = threadIdx.x;          // 0..511
  const int w0 = blockIdx.x * WPB;
  for (int i = tid; i < WPB*2*NHID; i += 512){
    int w = i >> 8; int j = i & (2*NHID-1);
    hcat[w][j] = (j < NHID) ? hseq[(w0+w)*NHID + j] : hq[(w0+w)*NHID + (j - NHID)];
  }
  __syncthreads();
  float acc[2][WPB];
  #pragma unroll
  for (int p=0;p<2;++p)
    #pragma unroll
    for (int w=0;w<WPB;++w) acc[p][w] = 0.0f;
  for (int j4 = 0; j4 < (2*NHID)/4; ++j4){
    f32x4 hv4[WPB];
    #pragma unroll
    for (int w=0; w<WPB; ++w) hv4[w] = *(const f32x4*)&hcat[w][j4*4];
    #pragma unroll
    for (int jj = 0; jj < 4; ++jj){
      int j = j4*4 + jj;
      float wv0 = clsWT[j*NEVENT + tid];
      float wv1 = clsWT[j*NEVENT + tid + 512];
      #pragma unroll
      for (int w=0; w<WPB; ++w){
        float hv = hv4[w][jj];
        acc[0][w] = fmaf(hv, wv0, acc[0][w]);
        acc[1][w] = fmaf(hv, wv1, acc[1][w]);
      }
    }
  }
  float bb0 = clsb[tid];
  float bb1 = clsb[tid + 512];
  #pragma unroll
  for (int w=0;w<WPB;++w){
    out[(w0+w)*NEVENT + tid]       = acc[0][w] + bb0;
    out[(w0+w)*NEVENT + tid + 512] = acc[1][w] + bb1;
  }
}

extern "C" void kernel_launch(void* const* d_in, const int* in_sizes, int n_in,
                              void* d_out, int out_size, void* d_ws, size_t ws_size,
                              hipStream_t stream) {
  const int*   seqtok = (const int*)  d_in[0];
  const float* sWih0  = (const float*)d_in[1];
  const float* sWhh0  = (const float*)d_in[2];
  const float* sb0i   = (const float*)d_in[3];
  const float* sb0h   = (const float*)d_in[4];
  const float* sWih1  = (const float*)d_in[5];
  const float* sWhh1  = (const float*)d_in[6];
  const float* sb1i   = (const float*)d_in[7];
  const float* sb1h   = (const float*)d_in[8];
  const float* qWih0  = (const float*)d_in[9];
  const float* qWhh0  = (const float*)d_in[10];
  const float* qb0i   = (const float*)d_in[11];
  const float* qb0h   = (const float*)d_in[12];
  const float* qWih1  = (const float*)d_in[13];
  const float* qWhh1  = (const float*)d_in[14];
  const float* qb1i   = (const float*)d_in[15];
  const float* qb1h   = (const float*)d_in[16];
  const float* clsW   = (const float*)d_in[17];
  const float* clsb   = (const float*)d_in[18];

  float* ws = (float*)d_ws;
  float* qWqT  = ws;                    // 1024*512 = 524288
  float* clsWT = ws + 524288;           // 256*1024 = 262144
  float* hseq  = ws + 786432;           // 2048*128 = 262144
  float* hq    = ws + 1048576;          // 262144
  unsigned short* pk = (unsigned short*)(ws + 1310720);
  unsigned short* pWhh0_s = pk;             // 6 matrices x 65536 ushorts
  unsigned short* pWih1_s = pk + 65536;
  unsigned short* pWhh1_s = pk + 131072;
  unsigned short* pWhh0_q = pk + 196608;
  unsigned short* pWih1_q = pk + 262144;
  unsigned short* pWhh1_q = pk + 327680;

  prep_k<<<960, 256, 0, stream>>>(qWih0, qWqT, clsW, clsWT,
      sWhh0, sWih1, sWhh1, qWhh0, qWih1, qWhh1, pk);

  lstm_fused_k<<<256, 1024, 0, stream>>>(seqtok, sWih0,
      sb0i, sb0h, sb1i, sb1h, qb0i, qb0h, qb1i, qb1h,
      pWhh0_s, pWih1_s, pWhh1_s, pWhh0_q, pWih1_q, pWhh1_q,
      qWqT, hseq, hq);

  cls_k<<<NWINDOW/WPB, 512, 0, stream>>>(hseq, hq, clsWT, clsb, (float*)d_out);
}

// Round 16
// 184.775 us; speedup vs baseline: 1.0804x; 1.0542x over previous
//
#include <hip/hip_runtime.h>
#include <hip/hip_bf16.h>
#include <math.h>

#define NEVENT 1024
#define NSTEP 64
#define NWINDOW 2048
#define NHID 128
#define NG 512
#define WPB 8   // windows per block in cls_k

typedef __attribute__((ext_vector_type(8))) short bf16x8;
typedef __attribute__((ext_vector_type(4))) float f32x4;

__device__ __forceinline__ unsigned short f2bf(float f){
  unsigned int u = __float_as_uint(f);
  return (unsigned short)((u + 0x7FFFu + ((u >> 16) & 1u)) >> 16);
}
__device__ __forceinline__ float sigm(float x){
  return __builtin_amdgcn_rcpf(1.0f + __expf(-x));
}
__device__ __forceinline__ float tanh_f(float x){
  float e = __expf(2.0f * x);
  return 1.0f - 2.0f * __builtin_amdgcn_rcpf(e + 1.0f);
}
// lgkm-only barrier: LDS ordering without draining vmcnt (global gathers stay in flight)
__device__ __forceinline__ void lgkm_barrier(){
  asm volatile("s_waitcnt lgkmcnt(0)" ::: "memory");
  __builtin_amdgcn_s_barrier();
}
// packed f32x2 -> bf16x2, RNE (bit-identical to f2bf); dst[15:0]=bf16(a), dst[31:16]=bf16(b)
__device__ __forceinline__ unsigned int cvtpk_bf16(float a, float b){
  unsigned int r;
  asm("v_cvt_pk_bf16_f32 %0, %1, %2" : "=v"(r) : "v"(a), "v"(b));
  return r;
}
// swizzle byte offset within h tile: spread rows across 16B slots
#define SWZ(row, byte) ((byte) ^ (((row) & 7) << 4))

// merged prep kernel:
//  blocks [0,512):   LDS-tiled transpose qWih0 [512][1024] -> qWqT [1024][512]
//  blocks [512,768): LDS-tiled transpose clsW  [1024][256] -> clsWT [256][1024]
//  blocks [768,960): pack6 (six W [512][128] f32 -> bf16 MFMA B-fragments)
__global__ __launch_bounds__(256)
void prep_k(const float* __restrict__ qWih0, float* __restrict__ qWqT,
            const float* __restrict__ clsW,  float* __restrict__ clsWT,
            const float* __restrict__ s0, const float* __restrict__ s1,
            const float* __restrict__ s2, const float* __restrict__ s3,
            const float* __restrict__ s4, const float* __restrict__ s5,
            unsigned short* __restrict__ dst)
{
  const int b = blockIdx.x;
  if (b < 768){
    // ---- tiled transpose: out[c][r] = in[r][c], both sides coalesced ----
    const float* in; float* out; int R, C, bb;
    if (b < 512){ in = qWih0; out = qWqT; R = NG;     C = NEVENT; bb = b; }
    else        { in = clsW;  out = clsWT; R = NEVENT; C = 2*NHID; bb = b - 512; }
    __shared__ float tl[32][33];
    const int nbx = C >> 5;
    const int by = bb / nbx, bx = bb - by*nbx;
    const int tx = threadIdx.x & 31, ty = threadIdx.x >> 5;
    #pragma unroll
    for (int k = 0; k < 4; ++k){
      int r = by*32 + ty + k*8;
      tl[ty + k*8][tx] = in[r*C + bx*32 + tx];
    }
    __syncthreads();
    #pragma unroll
    for (int k = 0; k < 4; ++k){
      int r = bx*32 + ty + k*8;               // out row = original col
      out[r*R + by*32 + tx] = tl[tx][ty + k*8];
    }
  } else {
    // ---- pack6: frag (kt,n): lane holds B[k][col], col=16n+(lane&15),
    // k=32kt+8*(lane>>4)+j, j=0..7 ----
    const int bb = b - 768;
    const int g = bb >> 5;
    const int i = (bb & 31)*256 + threadIdx.x;   // [0, 8192)
    const float* src = (g==0)?s0:(g==1)?s1:(g==2)?s2:(g==3)?s3:(g==4)?s4:s5;
    unsigned short* d = dst + g*65536;
    const int lane = i & 63; const int n = (i >> 6) & 31; const int kt = i >> 11;
    const int col = 16*n + (lane & 15);
    const int k0  = 32*kt + 8*(lane >> 4);
    #pragma unroll
    for (int j = 0; j < 8; ++j)
      d[i*8 + j] = f2bf(src[col*128 + k0 + j]);
  }
}

// R25 lstm = R24 lstm VERBATIM (verified ~167us; declared at floor: issue 84%
// occupied, transcendentals ~20% of VALU irreducible, spill closed after 6
// attempts, barrier structure minimal). Structure: role-split (waves 0-7 =
// L1/phase-C, 8-15 = L0/phase-A), one lgkm barrier/step, JIT quant gather,
// cvt_pk h-stores.
// Tripwires: absmax == 1.9531e-3 exactly; WRITE ~11.3MB / FETCH ~14.9MB.
__global__ __launch_bounds__(1024) __attribute__((amdgpu_waves_per_eu(4, 4)))
void lstm_fused_k(const int* __restrict__ seqtok,
    const float* __restrict__ sWih0,
    const float* __restrict__ sb0i, const float* __restrict__ sb0h,
    const float* __restrict__ sb1i, const float* __restrict__ sb1h,
    const float* __restrict__ qb0i, const float* __restrict__ qb0h,
    const float* __restrict__ qb1i, const float* __restrict__ qb1h,
    const unsigned short* __restrict__ pWhh0_s, const unsigned short* __restrict__ pWih1_s,
    const unsigned short* __restrict__ pWhh1_s,
    const unsigned short* __restrict__ pWhh0_q, const unsigned short* __restrict__ pWih1_q,
    const unsigned short* __restrict__ pWhh1_q,
    const float* __restrict__ qWqT,    // [1024][512]
    float* __restrict__ hseq, float* __restrict__ hq)
{
  __shared__ uint4 wih1[8192];                                            // 128 KB
  __shared__ __attribute__((aligned(16))) unsigned short h0buf[2][2048];  // 2 x 4KB
  __shared__ __attribute__((aligned(16))) unsigned short h1buf[2][2048];
  __shared__ int sAll[16*64];                                             // 4KB

  const int tid  = threadIdx.x;
  const int lane = tid & 63;
  const int w    = tid >> 6;            // wave id 0..15
  const bool quant = (blockIdx.x >= 128);
  const int blk  = quant ? (int)blockIdx.x - 128 : (int)blockIdx.x;
  const int w0   = blk * 16;

  // ---- prologue staging (all 16 waves) ----
  const uint4* wsrc = (const uint4*)(quant ? pWih1_q : pWih1_s);
  for (int i = tid; i < 8192; i += 1024) wih1[i] = wsrc[i];
  sAll[tid] = seqtok[w0*64 + tid];                       // [16 win][64 t] contiguous
  for (int i = tid; i < 2048; i += 1024){ h0buf[0][i] = 0; h1buf[0][i] = 0; }

  const int rbase = 4*(lane >> 4);         // window row base (D-layout)
  char* const h0base = (char*)h0buf;
  char* const h1base = (char*)h1buf;

  __syncthreads();   // barrier #0: staged data ready

  if (w < 8){
    // ================= L1 role: layer-1, phase C(t) =================
    const int nw   = w;
    const int jcol = 16*nw + (lane & 15);
    const float* b1i = quant ? qb1i : sb1i; const float* b1h = quant ? qb1h : sb1h;
    float b1c[4];
    #pragma unroll
    for (int q = 0; q < 4; ++q){ int col = 128*q + jcol; b1c[q] = b1i[col] + b1h[col]; }
    const unsigned short* p1 = quant ? pWhh1_q : pWhh1_s;
    bf16x8 whh1f[4][4];
    #pragma unroll
    for (int q = 0; q < 4; ++q)
      #pragma unroll
      for (int kt = 0; kt < 4; ++kt)
        whh1f[q][kt] = *(const bf16x8*)(p1 + ((kt*32 + 8*q + nw)*64 + lane)*8);
    float c1[4] = {0,0,0,0};
    float* const houtp = quant ? hq : hseq;

    lgkm_barrier();    // barrier #1: pairs with L0's post-A(0) barrier -> h0[0] ready

    for (int t = 0; t < NSTEP-1; ++t){
      char* h0rd = h0base + ((t+1)&1)*4096;   // h0[t]
      char* h1rd = h1base + ((t  )&1)*4096;   // h1[t-1]
      char* h1wr = h1base + ((t+1)&1)*4096;   // h1[t]
      f32x4 acc[4];
      #pragma unroll
      for (int q = 0; q < 4; ++q){ f32x4 a; a[0]=b1c[q]; a[1]=b1c[q]; a[2]=b1c[q]; a[3]=b1c[q]; acc[q] = a; }
      #pragma unroll
      for (int kt = 0; kt < 4; ++kt){
        int row = lane & 15;
        int off = SWZ(row, row*256 + kt*64 + (lane>>4)*16);
        const bf16x8 a0 = *(const bf16x8*)(h0rd + off);
        const bf16x8 a1 = *(const bf16x8*)(h1rd + off);
        #pragma unroll
        for (int q = 0; q < 4; ++q){
          const bf16x8 wi = *(const bf16x8*)((const char*)wih1 + ((kt*32 + 8*q + nw)*64 + lane)*16);
          acc[q] = __builtin_amdgcn_mfma_f32_16x16x32_bf16(a0, wi,           acc[q], 0, 0, 0);
          acc[q] = __builtin_amdgcn_mfma_f32_16x16x32_bf16(a1, whh1f[q][kt], acc[q], 0, 0, 0);
        }
      }
      {
        float hv[4];
        #pragma unroll
        for (int r = 0; r < 4; ++r){
          float iv = sigm(acc[0][r]), fv = sigm(acc[1][r]);
          float gv = tanh_f(acc[2][r]), ov = sigm(acc[3][r]);
          c1[r] = fv*c1[r] + iv*gv;
          hv[r] = ov * tanh_f(c1[r]);
        }
        unsigned int pk01 = cvtpk_bf16(hv[0], hv[1]);
        unsigned int pk23 = cvtpk_bf16(hv[2], hv[3]);
        *(unsigned short*)(h1wr + SWZ(rbase,   (rbase  )*256 + jcol*2)) = (unsigned short)pk01;
        *(unsigned short*)(h1wr + SWZ(rbase+1, (rbase+1)*256 + jcol*2)) = (unsigned short)(pk01 >> 16);
        *(unsigned short*)(h1wr + SWZ(rbase+2, (rbase+2)*256 + jcol*2)) = (unsigned short)pk23;
        *(unsigned short*)(h1wr + SWZ(rbase+3, (rbase+3)*256 + jcol*2)) = (unsigned short)(pk23 >> 16);
      }
      lgkm_barrier();
    }

    // ---- epilogue C(63): write global output only (L0 waves already done) ----
    {
      char* h0rd = h0base + 0*4096;           // h0[63] -> buf (63+1)&1 = 0
      char* h1rd = h1base + 1*4096;           // h1[62] -> buf 63&1 = 1
      f32x4 acc[4];
      #pragma unroll
      for (int q = 0; q < 4; ++q){ f32x4 a; a[0]=b1c[q]; a[1]=b1c[q]; a[2]=b1c[q]; a[3]=b1c[q]; acc[q] = a; }
      #pragma unroll
      for (int kt = 0; kt < 4; ++kt){
        int row = lane & 15;
        int off = SWZ(row, row*256 + kt*64 + (lane>>4)*16);
        const bf16x8 a0 = *(const bf16x8*)(h0rd + off);
        const bf16x8 a1 = *(const bf16x8*)(h1rd + off);
        #pragma unroll
        for (int q = 0; q < 4; ++q){
          const bf16x8 wi = *(const bf16x8*)((const char*)wih1 + ((kt*32 + 8*q + nw)*64 + lane)*16);
          acc[q] = __builtin_amdgcn_mfma_f32_16x16x32_bf16(a0, wi,           acc[q], 0, 0, 0);
          acc[q] = __builtin_amdgcn_mfma_f32_16x16x32_bf16(a1, whh1f[q][kt], acc[q], 0, 0, 0);
        }
      }
      #pragma unroll
      for (int r = 0; r < 4; ++r){
        float iv = sigm(acc[0][r]), fv = sigm(acc[1][r]);
        float gv = tanh_f(acc[2][r]), ov = sigm(acc[3][r]);
        c1[r] = fv*c1[r] + iv*gv;
        float h = ov * tanh_f(c1[r]);
        int row = rbase + r;
        houtp[(w0 + row)*128 + jcol] = h;
      }
    }
  } else {
    // ================= L0 role: layer-0, phase A(t+1) =================
    const int nw   = w - 8;
    const int jcol = 16*nw + (lane & 15);
    const float* b0i = quant ? qb0i : sb0i; const float* b0h = quant ? qb0h : sb0h;
    float b0c[4];
    #pragma unroll
    for (int q = 0; q < 4; ++q){
      int col = 128*q + jcol;
      b0c[q] = b0i[col] + b0h[col];
    }
    const unsigned short* p0 = quant ? pWhh0_q : pWhh0_s;
    bf16x8 whh0f[4][4];
    #pragma unroll
    for (int q = 0; q < 4; ++q)
      #pragma unroll
      for (int kt = 0; kt < 4; ++kt)
        whh0f[q][kt] = *(const bf16x8*)(p0 + ((kt*32 + 8*q + nw)*64 + lane)*8);

    float c0[4] = {0,0,0,0};

    if (quant){
      // ---- quant arm: R15 structure; h-store via cvt_pk (RNE-exact) ----
      float zr[4][4];
      #pragma unroll
      for (int q = 0; q < 4; ++q)
        #pragma unroll
        for (int r = 0; r < 4; ++r) zr[q][r] = b0c[q];
      // A(0): h[-1]=0; gather g(s_0) in place
      {
        float gvv[4][4];                // [q][r] transient
        #pragma unroll
        for (int r = 0; r < 4; ++r){
          int s = sAll[(rbase + r)*64 + 0];
          const float* gp = qWqT + s*512 + jcol;
          #pragma unroll
          for (int q = 0; q < 4; ++q) gvv[q][r] = gp[128*q];
        }
        float g0[4][4];
        #pragma unroll
        for (int q = 0; q < 4; ++q)
          #pragma unroll
          for (int r = 0; r < 4; ++r){ zr[q][r] += gvv[q][r]; g0[q][r] = zr[q][r]; }
        #pragma unroll
        for (int r = 0; r < 4; ++r){
          float iv = sigm(g0[0][r]);
          float gv = tanh_f(g0[2][r]);
          float ov = sigm(g0[3][r]);
          c0[r] = iv * gv;                 // f*c_prev = 0
          float h = ov * tanh_f(c0[r]);
          int row = rbase + r;
          *(unsigned short*)(h0base + 4096 + SWZ(row, row*256 + jcol*2)) = f2bf(h);  // h0[0] -> buf 1
        }
      }
      lgkm_barrier();    // barrier #1: h0[0] visible

      #pragma clang loop unroll(disable)
      for (int t = 0; t < NSTEP-1; ++t){
        char* h0rd = h0base + ((t+1)&1)*4096;   // h0[t]
        char* h0wr = h0base + ((t  )&1)*4096;   // h0[t+1]
        // JIT gather g(s_{t+1}) -- issued first, consumed at acc init below;
        // latency hides in L0's matrix-pipe slack vs the L1 waves.
        float gvv[4][4];                // [q][r] transient
        #pragma unroll
        for (int r = 0; r < 4; ++r){
          int s = sAll[(rbase + r)*64 + t + 1];
          const float* gp = qWqT + s*512 + jcol;
          #pragma unroll
          for (int q = 0; q < 4; ++q) gvv[q][r] = gp[128*q];
        }
        f32x4 acc[4];
        #pragma unroll
        for (int q = 0; q < 4; ++q){
          f32x4 a;
          #pragma unroll
          for (int r = 0; r < 4; ++r){ zr[q][r] += gvv[q][r]; a[r] = zr[q][r]; }
          acc[q] = a;
        }
        #pragma unroll
        for (int kt = 0; kt < 4; ++kt){
          int row = lane & 15;
          int off = SWZ(row, row*256 + kt*64 + (lane>>4)*16);
          const bf16x8 a0 = *(const bf16x8*)(h0rd + off);
          #pragma unroll
          for (int q = 0; q < 4; ++q)
            acc[q] = __builtin_amdgcn_mfma_f32_16x16x32_bf16(a0, whh0f[q][kt], acc[q], 0, 0, 0);
        }
        {
          float hv[4];
          #pragma unroll
          for (int r = 0; r < 4; ++r){
            float iv = sigm(acc[0][r]), fv = sigm(acc[1][r]);
            float gv = tanh_f(acc[2][r]), ov = sigm(acc[3][r]);
            c0[r] = fv*c0[r] + iv*gv;
            hv[r] = ov * tanh_f(c0[r]);
          }
          unsigned int pk01 = cvtpk_bf16(hv[0], hv[1]);
          unsigned int pk23 = cvtpk_bf16(hv[2], hv[3]);
          *(unsigned short*)(h0wr + SWZ(rbase,   (rbase  )*256 + jcol*2)) = (unsigned short)pk01;
          *(unsigned short*)(h0wr + SWZ(rbase+1, (rbase+1)*256 + jcol*2)) = (unsigned short)(pk01 >> 16);
          *(unsigned short*)(h0wr + SWZ(rbase+2, (rbase+2)*256 + jcol*2)) = (unsigned short)pk23;
          *(unsigned short*)(h0wr + SWZ(rbase+3, (rbase+3)*256 + jcol*2)) = (unsigned short)(pk23 >> 16);
        }
        lgkm_barrier();
      }
    } else {
      // ---- seq arm: input is the scalar token; wc lives only here ----
      float wc[4];
      #pragma unroll
      for (int q = 0; q < 4; ++q) wc[q] = sWih0[128*q + jcol];
      // A(0): h[-1]=0
      {
        float g0[4][4];
        #pragma unroll
        for (int r = 0; r < 4; ++r){
          float sv = (float)sAll[(rbase + r)*64 + 0];
          #pragma unroll
          for (int q = 0; q < 4; ++q) g0[q][r] = fmaf(sv, wc[q], b0c[q]);
        }
        #pragma unroll
        for (int r = 0; r < 4; ++r){
          float iv = sigm(g0[0][r]);
          float gv = tanh_f(g0[2][r]);
          float ov = sigm(g0[3][r]);
          c0[r] = iv * gv;                 // f*c_prev = 0
          float h = ov * tanh_f(c0[r]);
          int row = rbase + r;
          *(unsigned short*)(h0base + 4096 + SWZ(row, row*256 + jcol*2)) = f2bf(h);  // h0[0] -> buf 1
        }
      }
      lgkm_barrier();    // barrier #1: h0[0] visible

      #pragma clang loop unroll(disable)
      for (int t = 0; t < NSTEP-1; ++t){
        char* h0rd = h0base + ((t+1)&1)*4096;   // h0[t]
        char* h0wr = h0base + ((t  )&1)*4096;   // h0[t+1]
        f32x4 acc[4];
        float sv[4];
        #pragma unroll
        for (int r = 0; r < 4; ++r) sv[r] = (float)sAll[(rbase + r)*64 + t + 1];
        #pragma unroll
        for (int q = 0; q < 4; ++q){
          f32x4 a;
          #pragma unroll
          for (int r = 0; r < 4; ++r) a[r] = fmaf(sv[r], wc[q], b0c[q]);
          acc[q] = a;
        }
        #pragma unroll
        for (int kt = 0; kt < 4; ++kt){
          int row = lane & 15;
          int off = SWZ(row, row*256 + kt*64 + (lane>>4)*16);
          const bf16x8 a0 = *(const bf16x8*)(h0rd + off);
          #pragma unroll
          for (int q = 0; q < 4; ++q)
            acc[q] = __builtin_amdgcn_mfma_f32_16x16x32_bf16(a0, whh0f[q][kt], acc[q], 0, 0, 0);
        }
        {
          float hv[4];
          #pragma unroll
          for (int r = 0; r < 4; ++r){
            float iv = sigm(acc[0][r]), fv = sigm(acc[1][r]);
            float gv = tanh_f(acc[2][r]), ov = sigm(acc[3][r]);
            c0[r] = fv*c0[r] + iv*gv;
            hv[r] = ov * tanh_f(c0[r]);
          }
          unsigned int pk01 = cvtpk_bf16(hv[0], hv[1]);
          unsigned int pk23 = cvtpk_bf16(hv[2], hv[3]);
          *(unsigned short*)(h0wr + SWZ(rbase,   (rbase  )*256 + jcol*2)) = (unsigned short)pk01;
          *(unsigned short*)(h0wr + SWZ(rbase+1, (rbase+1)*256 + jcol*2)) = (unsigned short)(pk01 >> 16);
          *(unsigned short*)(h0wr + SWZ(rbase+2, (rbase+2)*256 + jcol*2)) = (unsigned short)pk23;
          *(unsigned short*)(h0wr + SWZ(rbase+3, (rbase+3)*256 + jcol*2)) = (unsigned short)(pk23 >> 16);
        }
        lgkm_barrier();
      }
    }
    // L0 done: 64 barriers executed, matching L1's count before its epilogue.
  }
}

// out[b][e] = dot(hcat[b], clsW[e]) + clsb[e]; clsWT is [256][1024].
// R25: 1024 threads (4 waves/SIMD), 1 event/thread, WPB=8, 256 blocks --
// same tiling/traffic as R23's verified cls, occupancy doubled again
// (R21's 1->2 waves bought ~8us; this tests 2->4 on the same curve).
__global__ __launch_bounds__(1024, 1)
void cls_k(const float* __restrict__ hseq, const float* __restrict__ hq,
           const float* __restrict__ clsWT, const float* __restrict__ clsb,
           float* __restrict__ out)
{
  __shared__ __attribute__((aligned(16))) float hcat[WPB][2*NHID];   // 8 KB
  const int tid = threadIdx.x;          // 0..1023 = event index
  const int w0 = blockIdx.x * WPB;
  for (int i = tid; i < WPB*2*NHID; i += 1024){
    int w = i >> 8; int j = i & (2*NHID-1);
    hcat[w][j] = (j < NHID) ? hseq[(w0+w)*NHID + j] : hq[(w0+w)*NHID + (j - NHID)];
  }
  __syncthreads();
  float acc[WPB];
  #pragma unroll
  for (int w=0;w<WPB;++w) acc[w] = 0.0f;
  for (int j4 = 0; j4 < (2*NHID)/4; ++j4){
    f32x4 hv4[WPB];
    #pragma unroll
    for (int w=0; w<WPB; ++w) hv4[w] = *(const f32x4*)&hcat[w][j4*4];
    #pragma unroll
    for (int jj = 0; jj < 4; ++jj){
      int j = j4*4 + jj;
      float wv = clsWT[j*NEVENT + tid];
      #pragma unroll
      for (int w=0; w<WPB; ++w)
        acc[w] = fmaf(hv4[w][jj], wv, acc[w]);
    }
  }
  float bb = clsb[tid];
  #pragma unroll
  for (int w=0;w<WPB;++w)
    out[(w0+w)*NEVENT + tid] = acc[w] + bb;
}

extern "C" void kernel_launch(void* const* d_in, const int* in_sizes, int n_in,
                              void* d_out, int out_size, void* d_ws, size_t ws_size,
                              hipStream_t stream) {
  const int*   seqtok = (const int*)  d_in[0];
  const float* sWih0  = (const float*)d_in[1];
  const float* sWhh0  = (const float*)d_in[2];
  const float* sb0i   = (const float*)d_in[3];
  const float* sb0h   = (const float*)d_in[4];
  const float* sWih1  = (const float*)d_in[5];
  const float* sWhh1  = (const float*)d_in[6];
  const float* sb1i   = (const float*)d_in[7];
  const float* sb1h   = (const float*)d_in[8];
  const float* qWih0  = (const float*)d_in[9];
  const float* qWhh0  = (const float*)d_in[10];
  const float* qb0i   = (const float*)d_in[11];
  const float* qb0h   = (const float*)d_in[12];
  const float* qWih1  = (const float*)d_in[13];
  const float* qWhh1  = (const float*)d_in[14];
  const float* qb1i   = (const float*)d_in[15];
  const float* qb1h   = (const float*)d_in[16];
  const float* clsW   = (const float*)d_in[17];
  const float* clsb   = (const float*)d_in[18];

  float* ws = (float*)d_ws;
  float* qWqT  = ws;                    // 1024*512 = 524288
  float* clsWT = ws + 524288;           // 256*1024 = 262144
  float* hseq  = ws + 786432;           // 2048*128 = 262144
  float* hq    = ws + 1048576;          // 262144
  unsigned short* pk = (unsigned short*)(ws + 1310720);
  unsigned short* pWhh0_s = pk;             // 6 matrices x 65536 ushorts
  unsigned short* pWih1_s = pk + 65536;
  unsigned short* pWhh1_s = pk + 131072;
  unsigned short* pWhh0_q = pk + 196608;
  unsigned short* pWih1_q = pk + 262144;
  unsigned short* pWhh1_q = pk + 327680;

  prep_k<<<960, 256, 0, stream>>>(qWih0, qWqT, clsW, clsWT,
      sWhh0, sWih1, sWhh1, qWhh0, qWih1, qWhh1, pk);

  lstm_fused_k<<<256, 1024, 0, stream>>>(seqtok, sWih0,
      sb0i, sb0h, sb1i, sb1h, qb0i, qb0h, qb1i, qb1h,
      pWhh0_s, pWih1_s, pWhh1_s, pWhh0_q, pWih1_q, pWhh1_q,
      qWqT, hseq, hq);

  cls_k<<<NWINDOW/WPB, 1024, 0, stream>>>(hseq, hq, clsWT, clsb, (float*)d_out);
}

// Round 17
// 180.119 us; speedup vs baseline: 1.1083x; 1.0258x over previous
//
#include <hip/hip_runtime.h>
#include <hip/hip_bf16.h>
#include <math.h>

#define NEVENT 1024
#define NSTEP 64
#define NWINDOW 2048
#define NHID 128
#define NG 512
#define WPB 8   // windows per block in cls_k

typedef __attribute__((ext_vector_type(8))) short bf16x8;
typedef __attribute__((ext_vector_type(4))) float f32x4;

__device__ __forceinline__ unsigned short f2bf(float f){
  unsigned int u = __float_as_uint(f);
  return (unsigned short)((u + 0x7FFFu + ((u >> 16) & 1u)) >> 16);
}
__device__ __forceinline__ float sigm(float x){
  return __builtin_amdgcn_rcpf(1.0f + __expf(-x));
}
__device__ __forceinline__ float tanh_f(float x){
  float e = __expf(2.0f * x);
  return 1.0f - 2.0f * __builtin_amdgcn_rcpf(e + 1.0f);
}
// lgkm-only barrier: LDS ordering without draining vmcnt (global gathers stay in flight)
__device__ __forceinline__ void lgkm_barrier(){
  asm volatile("s_waitcnt lgkmcnt(0)" ::: "memory");
  __builtin_amdgcn_s_barrier();
}
// packed f32x2 -> bf16x2, RNE (bit-identical to f2bf); dst[15:0]=bf16(a), dst[31:16]=bf16(b)
__device__ __forceinline__ unsigned int cvtpk_bf16(float a, float b){
  unsigned int r;
  asm("v_cvt_pk_bf16_f32 %0, %1, %2" : "=v"(r) : "v"(a), "v"(b));
  return r;
}
// swizzle byte offset within h tile: spread rows across 16B slots
#define SWZ(row, byte) ((byte) ^ (((row) & 7) << 4))

// merged prep kernel:
//  blocks [0,512):   LDS-tiled transpose qWih0 [512][1024] -> qWqT
//                    GATE-INTERLEAVED: qWqT[event][ (gate&127)*4 + (gate>>7) ]
//                    so the lstm quant gather reads one f32x4 per event-row.
//  blocks [512,768): LDS-tiled transpose clsW  [1024][256] -> clsWT [256][1024]
//  blocks [768,960): pack6 (six W [512][128] f32 -> bf16 MFMA B-fragments)
__global__ __launch_bounds__(256)
void prep_k(const float* __restrict__ qWih0, float* __restrict__ qWqT,
            const float* __restrict__ clsW,  float* __restrict__ clsWT,
            const float* __restrict__ s0, const float* __restrict__ s1,
            const float* __restrict__ s2, const float* __restrict__ s3,
            const float* __restrict__ s4, const float* __restrict__ s5,
            unsigned short* __restrict__ dst)
{
  const int b = blockIdx.x;
  if (b < 512){
    // ---- tiled transpose qWih0 -> gate-interleaved qWqT ----
    __shared__ float tl[32][33];
    const int nbx = NEVENT >> 5;
    const int by = b / nbx, bx = b - by*nbx;
    const int tx = threadIdx.x & 31, ty = threadIdx.x >> 5;
    #pragma unroll
    for (int k = 0; k < 4; ++k){
      int r = by*32 + ty + k*8;                 // gate row
      tl[ty + k*8][tx] = qWih0[r*NEVENT + bx*32 + tx];
    }
    __syncthreads();
    #pragma unroll
    for (int k = 0; k < 4; ++k){
      int ev   = bx*32 + ty + k*8;              // event (original col)
      int gate = by*32 + tx;
      int q    = gate >> 7;
      int jc   = gate & 127;
      qWqT[ev*512 + jc*4 + q] = tl[tx][ty + k*8];
    }
  } else if (b < 768){
    // ---- tiled transpose clsW -> clsWT (unchanged) ----
    const int bb = b - 512;
    __shared__ float tl[32][33];
    const int nbx = (2*NHID) >> 5;
    const int by = bb / nbx, bx = bb - by*nbx;
    const int tx = threadIdx.x & 31, ty = threadIdx.x >> 5;
    #pragma unroll
    for (int k = 0; k < 4; ++k){
      int r = by*32 + ty + k*8;
      tl[ty + k*8][tx] = clsW[r*(2*NHID) + bx*32 + tx];
    }
    __syncthreads();
    #pragma unroll
    for (int k = 0; k < 4; ++k){
      int r = bx*32 + ty + k*8;                 // out row = original col
      clsWT[r*NEVENT + by*32 + tx] = tl[tx][ty + k*8];
    }
  } else {
    // ---- pack6: frag (kt,n): lane holds B[k][col], col=16n+(lane&15),
    // k=32kt+8*(lane>>4)+j, j=0..7 ----
    const int bb = b - 768;
    const int g = bb >> 5;
    const int i = (bb & 31)*256 + threadIdx.x;   // [0, 8192)
    const float* src = (g==0)?s0:(g==1)?s1:(g==2)?s2:(g==3)?s3:(g==4)?s4:s5;
    unsigned short* d = dst + g*65536;
    const int lane = i & 63; const int n = (i >> 6) & 31; const int kt = i >> 11;
    const int col = 16*n + (lane & 15);
    const int k0  = 32*kt + 8*(lane >> 4);
    #pragma unroll
    for (int j = 0; j < 8; ++j)
      d[i*8 + j] = f2bf(src[col*128 + k0 + j]);
  }
}

// R26 lstm = R25 lstm with the quant gather VECTORIZED via the gate-interleaved
// qWqT layout: 16 scalar loads + 16 addr calcs per step -> 4 f32x4 loads + 4.
// zr accumulation keeps the exact q-outer/r-inner order (reads gvv[r][q]) ->
// bit-identical. L1/seq arms verbatim (declared floor ~167us).
// Tripwires: absmax == 1.9531e-3 exactly; WRITE <= 11.3MB / lstm <= 168us
// (else revert to R25 and declare).
__global__ __launch_bounds__(1024) __attribute__((amdgpu_waves_per_eu(4, 4)))
void lstm_fused_k(const int* __restrict__ seqtok,
    const float* __restrict__ sWih0,
    const float* __restrict__ sb0i, const float* __restrict__ sb0h,
    const float* __restrict__ sb1i, const float* __restrict__ sb1h,
    const float* __restrict__ qb0i, const float* __restrict__ qb0h,
    const float* __restrict__ qb1i, const float* __restrict__ qb1h,
    const unsigned short* __restrict__ pWhh0_s, const unsigned short* __restrict__ pWih1_s,
    const unsigned short* __restrict__ pWhh1_s,
    const unsigned short* __restrict__ pWhh0_q, const unsigned short* __restrict__ pWih1_q,
    const unsigned short* __restrict__ pWhh1_q,
    const float* __restrict__ qWqT,    // [1024][128 jcol x 4 q] gate-interleaved
    float* __restrict__ hseq, float* __restrict__ hq)
{
  __shared__ uint4 wih1[8192];                                            // 128 KB
  __shared__ __attribute__((aligned(16))) unsigned short h0buf[2][2048];  // 2 x 4KB
  __shared__ __attribute__((aligned(16))) unsigned short h1buf[2][2048];
  __shared__ int sAll[16*64];                                             // 4KB

  const int tid  = threadIdx.x;
  const int lane = tid & 63;
  const int w    = tid >> 6;            // wave id 0..15
  const bool quant = (blockIdx.x >= 128);
  const int blk  = quant ? (int)blockIdx.x - 128 : (int)blockIdx.x;
  const int w0   = blk * 16;

  // ---- prologue staging (all 16 waves) ----
  const uint4* wsrc = (const uint4*)(quant ? pWih1_q : pWih1_s);
  for (int i = tid; i < 8192; i += 1024) wih1[i] = wsrc[i];
  sAll[tid] = seqtok[w0*64 + tid];                       // [16 win][64 t] contiguous
  for (int i = tid; i < 2048; i += 1024){ h0buf[0][i] = 0; h1buf[0][i] = 0; }

  const int rbase = 4*(lane >> 4);         // window row base (D-layout)
  char* const h0base = (char*)h0buf;
  char* const h1base = (char*)h1buf;

  __syncthreads();   // barrier #0: staged data ready

  if (w < 8){
    // ================= L1 role: layer-1, phase C(t) =================
    const int nw   = w;
    const int jcol = 16*nw + (lane & 15);
    const float* b1i = quant ? qb1i : sb1i; const float* b1h = quant ? qb1h : sb1h;
    float b1c[4];
    #pragma unroll
    for (int q = 0; q < 4; ++q){ int col = 128*q + jcol; b1c[q] = b1i[col] + b1h[col]; }
    const unsigned short* p1 = quant ? pWhh1_q : pWhh1_s;
    bf16x8 whh1f[4][4];
    #pragma unroll
    for (int q = 0; q < 4; ++q)
      #pragma unroll
      for (int kt = 0; kt < 4; ++kt)
        whh1f[q][kt] = *(const bf16x8*)(p1 + ((kt*32 + 8*q + nw)*64 + lane)*8);
    float c1[4] = {0,0,0,0};
    float* const houtp = quant ? hq : hseq;

    lgkm_barrier();    // barrier #1: pairs with L0's post-A(0) barrier -> h0[0] ready

    for (int t = 0; t < NSTEP-1; ++t){
      char* h0rd = h0base + ((t+1)&1)*4096;   // h0[t]
      char* h1rd = h1base + ((t  )&1)*4096;   // h1[t-1]
      char* h1wr = h1base + ((t+1)&1)*4096;   // h1[t]
      f32x4 acc[4];
      #pragma unroll
      for (int q = 0; q < 4; ++q){ f32x4 a; a[0]=b1c[q]; a[1]=b1c[q]; a[2]=b1c[q]; a[3]=b1c[q]; acc[q] = a; }
      #pragma unroll
      for (int kt = 0; kt < 4; ++kt){
        int row = lane & 15;
        int off = SWZ(row, row*256 + kt*64 + (lane>>4)*16);
        const bf16x8 a0 = *(const bf16x8*)(h0rd + off);
        const bf16x8 a1 = *(const bf16x8*)(h1rd + off);
        #pragma unroll
        for (int q = 0; q < 4; ++q){
          const bf16x8 wi = *(const bf16x8*)((const char*)wih1 + ((kt*32 + 8*q + nw)*64 + lane)*16);
          acc[q] = __builtin_amdgcn_mfma_f32_16x16x32_bf16(a0, wi,           acc[q], 0, 0, 0);
          acc[q] = __builtin_amdgcn_mfma_f32_16x16x32_bf16(a1, whh1f[q][kt], acc[q], 0, 0, 0);
        }
      }
      {
        float hv[4];
        #pragma unroll
        for (int r = 0; r < 4; ++r){
          float iv = sigm(acc[0][r]), fv = sigm(acc[1][r]);
          float gv = tanh_f(acc[2][r]), ov = sigm(acc[3][r]);
          c1[r] = fv*c1[r] + iv*gv;
          hv[r] = ov * tanh_f(c1[r]);
        }
        unsigned int pk01 = cvtpk_bf16(hv[0], hv[1]);
        unsigned int pk23 = cvtpk_bf16(hv[2], hv[3]);
        *(unsigned short*)(h1wr + SWZ(rbase,   (rbase  )*256 + jcol*2)) = (unsigned short)pk01;
        *(unsigned short*)(h1wr + SWZ(rbase+1, (rbase+1)*256 + jcol*2)) = (unsigned short)(pk01 >> 16);
        *(unsigned short*)(h1wr + SWZ(rbase+2, (rbase+2)*256 + jcol*2)) = (unsigned short)pk23;
        *(unsigned short*)(h1wr + SWZ(rbase+3, (rbase+3)*256 + jcol*2)) = (unsigned short)(pk23 >> 16);
      }
      lgkm_barrier();
    }

    // ---- epilogue C(63): write global output only (L0 waves already done) ----
    {
      char* h0rd = h0base + 0*4096;           // h0[63] -> buf (63+1)&1 = 0
      char* h1rd = h1base + 1*4096;           // h1[62] -> buf 63&1 = 1
      f32x4 acc[4];
      #pragma unroll
      for (int q = 0; q < 4; ++q){ f32x4 a; a[0]=b1c[q]; a[1]=b1c[q]; a[2]=b1c[q]; a[3]=b1c[q]; acc[q] = a; }
      #pragma unroll
      for (int kt = 0; kt < 4; ++kt){
        int row = lane & 15;
        int off = SWZ(row, row*256 + kt*64 + (lane>>4)*16);
        const bf16x8 a0 = *(const bf16x8*)(h0rd + off);
        const bf16x8 a1 = *(const bf16x8*)(h1rd + off);
        #pragma unroll
        for (int q = 0; q < 4; ++q){
          const bf16x8 wi = *(const bf16x8*)((const char*)wih1 + ((kt*32 + 8*q + nw)*64 + lane)*16);
          acc[q] = __builtin_amdgcn_mfma_f32_16x16x32_bf16(a0, wi,           acc[q], 0, 0, 0);
          acc[q] = __builtin_amdgcn_mfma_f32_16x16x32_bf16(a1, whh1f[q][kt], acc[q], 0, 0, 0);
        }
      }
      #pragma unroll
      for (int r = 0; r < 4; ++r){
        float iv = sigm(acc[0][r]), fv = sigm(acc[1][r]);
        float gv = tanh_f(acc[2][r]), ov = sigm(acc[3][r]);
        c1[r] = fv*c1[r] + iv*gv;
        float h = ov * tanh_f(c1[r]);
        int row = rbase + r;
        houtp[(w0 + row)*128 + jcol] = h;
      }
    }
  } else {
    // ================= L0 role: layer-0, phase A(t+1) =================
    const int nw   = w - 8;
    const int jcol = 16*nw + (lane & 15);
    const float* b0i = quant ? qb0i : sb0i; const float* b0h = quant ? qb0h : sb0h;
    float b0c[4];
    #pragma unroll
    for (int q = 0; q < 4; ++q){
      int col = 128*q + jcol;
      b0c[q] = b0i[col] + b0h[col];
    }
    const unsigned short* p0 = quant ? pWhh0_q : pWhh0_s;
    bf16x8 whh0f[4][4];
    #pragma unroll
    for (int q = 0; q < 4; ++q)
      #pragma unroll
      for (int kt = 0; kt < 4; ++kt)
        whh0f[q][kt] = *(const bf16x8*)(p0 + ((kt*32 + 8*q + nw)*64 + lane)*8);

    float c0[4] = {0,0,0,0};

    if (quant){
      // ---- quant arm: vectorized gather (one f32x4 per event-row) ----
      const float* const gq = qWqT + jcol*4;   // per-lane base into interleaved layout
      float zr[4][4];
      #pragma unroll
      for (int q = 0; q < 4; ++q)
        #pragma unroll
        for (int r = 0; r < 4; ++r) zr[q][r] = b0c[q];
      // A(0): h[-1]=0; gather g(s_0) in place
      {
        f32x4 gvv[4];                   // [r] -> 4 gates
        #pragma unroll
        for (int r = 0; r < 4; ++r){
          int s = sAll[(rbase + r)*64 + 0];
          gvv[r] = *(const f32x4*)(gq + s*512);
        }
        float g0[4][4];
        #pragma unroll
        for (int q = 0; q < 4; ++q)
          #pragma unroll
          for (int r = 0; r < 4; ++r){ zr[q][r] += gvv[r][q]; g0[q][r] = zr[q][r]; }
        #pragma unroll
        for (int r = 0; r < 4; ++r){
          float iv = sigm(g0[0][r]);
          float gv = tanh_f(g0[2][r]);
          float ov = sigm(g0[3][r]);
          c0[r] = iv * gv;                 // f*c_prev = 0
          float h = ov * tanh_f(c0[r]);
          int row = rbase + r;
          *(unsigned short*)(h0base + 4096 + SWZ(row, row*256 + jcol*2)) = f2bf(h);  // h0[0] -> buf 1
        }
      }
      lgkm_barrier();    // barrier #1: h0[0] visible

      #pragma clang loop unroll(disable)
      for (int t = 0; t < NSTEP-1; ++t){
        char* h0rd = h0base + ((t+1)&1)*4096;   // h0[t]
        char* h0wr = h0base + ((t  )&1)*4096;   // h0[t+1]
        // JIT vector gather g(s_{t+1}) -- 4 f32x4 loads, consumed at zr below
        f32x4 gvv[4];                   // [r] -> 4 gates
        #pragma unroll
        for (int r = 0; r < 4; ++r){
          int s = sAll[(rbase + r)*64 + t + 1];
          gvv[r] = *(const f32x4*)(gq + s*512);
        }
        f32x4 acc[4];
        #pragma unroll
        for (int q = 0; q < 4; ++q){
          f32x4 a;
          #pragma unroll
          for (int r = 0; r < 4; ++r){ zr[q][r] += gvv[r][q]; a[r] = zr[q][r]; }
          acc[q] = a;
        }
        #pragma unroll
        for (int kt = 0; kt < 4; ++kt){
          int row = lane & 15;
          int off = SWZ(row, row*256 + kt*64 + (lane>>4)*16);
          const bf16x8 a0 = *(const bf16x8*)(h0rd + off);
          #pragma unroll
          for (int q = 0; q < 4; ++q)
            acc[q] = __builtin_amdgcn_mfma_f32_16x16x32_bf16(a0, whh0f[q][kt], acc[q], 0, 0, 0);
        }
        {
          float hv[4];
          #pragma unroll
          for (int r = 0; r < 4; ++r){
            float iv = sigm(acc[0][r]), fv = sigm(acc[1][r]);
            float gv = tanh_f(acc[2][r]), ov = sigm(acc[3][r]);
            c0[r] = fv*c0[r] + iv*gv;
            hv[r] = ov * tanh_f(c0[r]);
          }
          unsigned int pk01 = cvtpk_bf16(hv[0], hv[1]);
          unsigned int pk23 = cvtpk_bf16(hv[2], hv[3]);
          *(unsigned short*)(h0wr + SWZ(rbase,   (rbase  )*256 + jcol*2)) = (unsigned short)pk01;
          *(unsigned short*)(h0wr + SWZ(rbase+1, (rbase+1)*256 + jcol*2)) = (unsigned short)(pk01 >> 16);
          *(unsigned short*)(h0wr + SWZ(rbase+2, (rbase+2)*256 + jcol*2)) = (unsigned short)pk23;
          *(unsigned short*)(h0wr + SWZ(rbase+3, (rbase+3)*256 + jcol*2)) = (unsigned short)(pk23 >> 16);
        }
        lgkm_barrier();
      }
    } else {
      // ---- seq arm: input is the scalar token; wc lives only here ----
      float wc[4];
      #pragma unroll
      for (int q = 0; q < 4; ++q) wc[q] = sWih0[128*q + jcol];
      // A(0): h[-1]=0
      {
        float g0[4][4];
        #pragma unroll
        for (int r = 0; r < 4; ++r){
          float sv = (float)sAll[(rbase + r)*64 + 0];
          #pragma unroll
          for (int q = 0; q < 4; ++q) g0[q][r] = fmaf(sv, wc[q], b0c[q]);
        }
        #pragma unroll
        for (int r = 0; r < 4; ++r){
          float iv = sigm(g0[0][r]);
          float gv = tanh_f(g0[2][r]);
          float ov = sigm(g0[3][r]);
          c0[r] = iv * gv;                 // f*c_prev = 0
          float h = ov * tanh_f(c0[r]);
          int row = rbase + r;
          *(unsigned short*)(h0base + 4096 + SWZ(row, row*256 + jcol*2)) = f2bf(h);  // h0[0] -> buf 1
        }
      }
      lgkm_barrier();    // barrier #1: h0[0] visible

      #pragma clang loop unroll(disable)
      for (int t = 0; t < NSTEP-1; ++t){
        char* h0rd = h0base + ((t+1)&1)*4096;   // h0[t]
        char* h0wr = h0base + ((t  )&1)*4096;   // h0[t+1]
        f32x4 acc[4];
        float sv[4];
        #pragma unroll
        for (int r = 0; r < 4; ++r) sv[r] = (float)sAll[(rbase + r)*64 + t + 1];
        #pragma unroll
        for (int q = 0; q < 4; ++q){
          f32x4 a;
          #pragma unroll
          for (int r = 0; r < 4; ++r) a[r] = fmaf(sv[r], wc[q], b0c[q]);
          acc[q] = a;
        }
        #pragma unroll
        for (int kt = 0; kt < 4; ++kt){
          int row = lane & 15;
          int off = SWZ(row, row*256 + kt*64 + (lane>>4)*16);
          const bf16x8 a0 = *(const bf16x8*)(h0rd + off);
          #pragma unroll
          for (int q = 0; q < 4; ++q)
            acc[q] = __builtin_amdgcn_mfma_f32_16x16x32_bf16(a0, whh0f[q][kt], acc[q], 0, 0, 0);
        }
        {
          float hv[4];
          #pragma unroll
          for (int r = 0; r < 4; ++r){
            float iv = sigm(acc[0][r]), fv = sigm(acc[1][r]);
            float gv = tanh_f(acc[2][r]), ov = sigm(acc[3][r]);
            c0[r] = fv*c0[r] + iv*gv;
            hv[r] = ov * tanh_f(c0[r]);
          }
          unsigned int pk01 = cvtpk_bf16(hv[0], hv[1]);
          unsigned int pk23 = cvtpk_bf16(hv[2], hv[3]);
          *(unsigned short*)(h0wr + SWZ(rbase,   (rbase  )*256 + jcol*2)) = (unsigned short)pk01;
          *(unsigned short*)(h0wr + SWZ(rbase+1, (rbase+1)*256 + jcol*2)) = (unsigned short)(pk01 >> 16);
          *(unsigned short*)(h0wr + SWZ(rbase+2, (rbase+2)*256 + jcol*2)) = (unsigned short)pk23;
          *(unsigned short*)(h0wr + SWZ(rbase+3, (rbase+3)*256 + jcol*2)) = (unsigned short)(pk23 >> 16);
        }
        lgkm_barrier();
      }
    }
    // L0 done: 64 barriers executed, matching L1's count before its epilogue.
  }
}

// out[b][e] = dot(hcat[b], clsW[e]) + clsb[e]; clsWT is [256][1024].
// R26 cls = R25 cls VERBATIM (verified ~10us, ~74% of L2 BW): 1024 threads
// (4 waves/SIMD), 1 event/thread, WPB=8, 256 blocks, f32x4 hcat reads.
__global__ __launch_bounds__(1024, 1)
void cls_k(const float* __restrict__ hseq, const float* __restrict__ hq,
           const float* __restrict__ clsWT, const float* __restrict__ clsb,
           float* __restrict__ out)
{
  __shared__ __attribute__((aligned(16))) float hcat[WPB][2*NHID];   // 8 KB
  const int tid = threadIdx.x;          // 0..1023 = event index
  const int w0 = blockIdx.x * WPB;
  for (int i = tid; i < WPB*2*NHID; i += 1024){
    int w = i >> 8; int j = i & (2*NHID-1);
    hcat[w][j] = (j < NHID) ? hseq[(w0+w)*NHID + j] : hq[(w0+w)*NHID + (j - NHID)];
  }
  __syncthreads();
  float acc[WPB];
  #pragma unroll
  for (int w=0;w<WPB;++w) acc[w] = 0.0f;
  for (int j4 = 0; j4 < (2*NHID)/4; ++j4){
    f32x4 hv4[WPB];
    #pragma unroll
    for (int w=0; w<WPB; ++w) hv4[w] = *(const f32x4*)&hcat[w][j4*4];
    #pragma unroll
    for (int jj = 0; jj < 4; ++jj){
      int j = j4*4 + jj;
      float wv = clsWT[j*NEVENT + tid];
      #pragma unroll
      for (int w=0; w<WPB; ++w)
        acc[w] = fmaf(hv4[w][jj], wv, acc[w]);
    }
  }
  float bb = clsb[tid];
  #pragma unroll
  for (int w=0;w<WPB;++w)
    out[(w0+w)*NEVENT + tid] = acc[w] + bb;
}

extern "C" void kernel_launch(void* const* d_in, const int* in_sizes, int n_in,
                              void* d_out, int out_size, void* d_ws, size_t ws_size,
                              hipStream_t stream) {
  const int*   seqtok = (const int*)  d_in[0];
  const float* sWih0  = (const float*)d_in[1];
  const float* sWhh0  = (const float*)d_in[2];
  const float* sb0i   = (const float*)d_in[3];
  const float* sb0h   = (const float*)d_in[4];
  const float* sWih1  = (const float*)d_in[5];
  const float* sWhh1  = (const float*)d_in[6];
  const float* sb1i   = (const float*)d_in[7];
  const float* sb1h   = (const float*)d_in[8];
  const float* qWih0  = (const float*)d_in[9];
  const float* qWhh0  = (const float*)d_in[10];
  const float* qb0i   = (const float*)d_in[11];
  const float* qb0h   = (const float*)d_in[12];
  const float* qWih1  = (const float*)d_in[13];
  const float* qWhh1  = (const float*)d_in[14];
  const float* qb1i   = (const float*)d_in[15];
  const float* qb1h   = (const float*)d_in[16];
  const float* clsW   = (const float*)d_in[17];
  const float* clsb   = (const float*)d_in[18];

  float* ws = (float*)d_ws;
  float* qWqT  = ws;                    // 1024*512 = 524288 (gate-interleaved)
  float* clsWT = ws + 524288;           // 256*1024 = 262144
  float* hseq  = ws + 786432;           // 2048*128 = 262144
  float* hq    = ws + 1048576;          // 262144
  unsigned short* pk = (unsigned short*)(ws + 1310720);
  unsigned short* pWhh0_s = pk;             // 6 matrices x 65536 ushorts
  unsigned short* pWih1_s = pk + 65536;
  unsigned short* pWhh1_s = pk + 131072;
  unsigned short* pWhh0_q = pk + 196608;
  unsigned short* pWih1_q = pk + 262144;
  unsigned short* pWhh1_q = pk + 327680;

  prep_k<<<960, 256, 0, stream>>>(qWih0, qWqT, clsW, clsWT,
      sWhh0, sWih1, sWhh1, qWhh0, qWih1, qWhh1, pk);

  lstm_fused_k<<<256, 1024, 0, stream>>>(seqtok, sWih0,
      sb0i, sb0h, sb1i, sb1h, qb0i, qb0h, qb1i, qb1h,
      pWhh0_s, pWih1_s, pWhh1_s, pWhh0_q, pWih1_q, pWhh1_q,
      qWqT, hseq, hq);

  cls_k<<<NWINDOW/WPB, 1024, 0, stream>>>(hseq, hq, clsWT, clsb, (float*)d_out);
}